// Round 10
// baseline (267.424 us; speedup 1.0000x reference)
//
#include <hip/hip_runtime.h>

// TransformerBlock on MI355X (gfx950).
// v19: gemm_in BK=32 -> BK=64, SAME structure as measured-best v14 (single
// LDS buffer, __syncthreads pair, compiler-scheduled, plain grid). Halves the
// number of barrier drains (32->16) that the 4-variant experiment (v14-v17)
// identified as the cost: each drain exposes ~const latency, so amortizing
// over 2x compute per step should cut stall time ~2x. LDS 16->32KB (no
// occupancy cliff; grid caps at 3 blocks/CU). Everything else = v18.

typedef __bf16 bf16;
typedef bf16 bf16x8 __attribute__((ext_vector_type(8)));
typedef bf16 bf16x4 __attribute__((ext_vector_type(4)));
typedef float f32x4 __attribute__((ext_vector_type(4)));
typedef float f32x16 __attribute__((ext_vector_type(16)));

#define EMB 1024
#define SEQ 2048
#define NTOK 4096
#define NH 16
#define HD 64

__device__ __forceinline__ f32x4 mfma16(bf16x8 a, bf16x8 b, f32x4 c) {
  return __builtin_amdgcn_mfma_f32_16x16x32_bf16(a, b, c, 0, 0, 0);
}
__device__ __forceinline__ f32x16 mfma32(bf16x8 a, bf16x8 b, f32x16 c) {
  return __builtin_amdgcn_mfma_f32_32x32x16_bf16(a, b, c, 0, 0, 0);
}

__device__ __forceinline__ void gll16(const void* g, void* l) {
  __builtin_amdgcn_global_load_lds(
      (const __attribute__((address_space(1))) void*)g,
      (__attribute__((address_space(3))) void*)l, 16, 0, 0);
}

__device__ __forceinline__ unsigned pk2(float a, float b) {
  union { bf16 h[2]; unsigned u; } t;
  t.h[0] = (bf16)a; t.h[1] = (bf16)b;
  return t.u;
}

// XCD-chunked swizzle (nwg % 8 == 0): each XCD gets a contiguous work chunk.
__device__ __forceinline__ void xcd_map(int nx, int nwg, int& bx, int& by) {
  const int lin = blockIdx.y * nx + blockIdx.x;
  const int id = (lin & 7) * (nwg >> 3) + (lin >> 3);
  bx = id % nx;
  by = id / nx;
}

// ---------------- fused elementwise prep (rope+cast, one launch) ----------
__global__ __launch_bounds__(256) void prep_all(
    const float* __restrict__ x, bf16* __restrict__ xb, bf16* __restrict__ qr,
    const float* __restrict__ w0, const float* __restrict__ w1,
    const float* __restrict__ w2, bf16* __restrict__ o0,
    bf16* __restrict__ o1, bf16* __restrict__ o2) {
  const int bid = blockIdx.x;
  if (bid < 8192) {
    int idx = bid * 256 + threadIdx.x;
    int row = idx >> 9;
    int i = idx & 511;
    int h = i >> 5, d2 = i & 31;
    int pos = row & (SEQ - 1);
    int c0 = h * HD + d2;
    size_t base = (size_t)row * EMB;
    float x0 = x[base + c0], x1 = x[base + c0 + 32];
    float invf = exp2f(-(float)d2 * 0.4152410118609203f);
    float ang = (float)pos * invf;
    float sn, cs;
    sincosf(ang, &sn, &cs);
    qr[base + c0] = (bf16)(x0 * cs - x1 * sn);
    qr[base + c0 + 32] = (bf16)(x1 * cs + x0 * sn);
    xb[base + c0] = (bf16)x0;
    xb[base + c0 + 32] = (bf16)x1;
  } else {
    int i = ((bid - 8192) * 256 + threadIdx.x) * 4;
    const float* s; bf16* d; int off;
    if (i < 3 * 1024 * 1024) { s = w0; d = o0; off = i; }
    else if (i < 4 * 1024 * 1024) { s = w1; d = o1; off = i - 3 * 1024 * 1024; }
    else { s = w2; d = o2; off = i - 4 * 1024 * 1024; }
    float4 f = *(const float4*)(s + off);
    d[off] = (bf16)f.x; d[off + 1] = (bf16)f.y;
    d[off + 2] = (bf16)f.z; d[off + 3] = (bf16)f.w;
  }
}

// ---------------- fused in-proj GEMM (v14 structure, BK=64) ----------------
// Outputs: qb[token][1024] pre-scaled by 0.125; kv images per (b,h): 32 tiles
// of 64 keys {K 4096 | V 4096} in the attention LDS layout (K scaled log2e).
__global__ __launch_bounds__(256) void gemm_in(
    const bf16* __restrict__ Aq, const bf16* __restrict__ Ax,
    const bf16* __restrict__ W, const float* __restrict__ bias,
    bf16* __restrict__ qb, bf16* __restrict__ kv) {
  __shared__ bf16 As[128 * 64];
  __shared__ bf16 Bs[128 * 64];
  const int tid = threadIdx.x, lane = tid & 63, wave = tid >> 6;
  const int quad = lane >> 4, l16 = lane & 15;
  const int m0 = blockIdx.y * 128, n0 = blockIdx.x * 128;
  const bf16* A = (n0 < 2048) ? Aq : Ax;
  const int K = 1024;
  const int wm = (wave >> 1) * 64, wn = (wave & 1) * 64;
  const int srow = wave * 32 + (lane >> 3);   // 8 rows per gll16 pass
  const int scol = (lane & 7) * 8;
  f32x4 acc[4][4] = {};
  for (int k0 = 0; k0 < K; k0 += 64) {
    __syncthreads();
#pragma unroll
    for (int p = 0; p < 4; ++p) {
      gll16(A + (size_t)(m0 + srow + p * 8) * K + k0 + scol,
            As + (wave * 32 + p * 8) * 64 + lane * 8);
      gll16(W + (size_t)(n0 + srow + p * 8) * K + k0 + scol,
            Bs + (wave * 32 + p * 8) * 64 + lane * 8);
    }
    __syncthreads();
#pragma unroll
    for (int kk = 0; kk < 2; ++kk) {
      bf16x8 af[4], bw[4];
#pragma unroll
      for (int t = 0; t < 4; ++t) {
        af[t] = *(const bf16x8*)(As + (wm + t * 16 + l16) * 64 + kk * 32 + quad * 8);
        bw[t] = *(const bf16x8*)(Bs + (wn + t * 16 + l16) * 64 + kk * 32 + quad * 8);
      }
#pragma unroll
      for (int mt = 0; mt < 4; ++mt)
#pragma unroll
        for (int nt = 0; nt < 4; ++nt)
          acc[mt][nt] = mfma16(af[mt], bw[nt], acc[mt][nt]);
    }
  }
  if (n0 < 1024) {
    // Q: scale 1/8 (exact in bf16)
#pragma unroll
    for (int mt = 0; mt < 4; ++mt)
      for (int nt = 0; nt < 4; ++nt) {
        const int n = n0 + wn + nt * 16 + l16;
        const float bv = bias[n];
#pragma unroll
        for (int r = 0; r < 4; ++r) {
          const int m = m0 + wm + mt * 16 + quad * 4 + r;
          qb[(size_t)m * 1024 + n] = (bf16)((acc[mt][nt][r] + bv) * 0.125f);
        }
      }
  } else if (n0 < 2048) {
    // K: scale log2(e), write into swizzled 64-key tile image
#pragma unroll
    for (int mt = 0; mt < 4; ++mt)
      for (int nt = 0; nt < 4; ++nt) {
        const int n = n0 + wn + nt * 16 + l16;
        const float bv = bias[n];
        const int kd = n - 1024, hh = kd >> 6, d = kd & 63;
        const int dc = d >> 3, dl = d & 7;
#pragma unroll
        for (int r = 0; r < 4; ++r) {
          const int m = m0 + wm + mt * 16 + quad * 4 + r;
          const int bb = m >> 11, s = m & 2047;
          const int t = s >> 6, kr = s & 63;
          const size_t base = ((size_t)((bb * 16 + hh) * 32 + t)) * 8192;
          kv[base + kr * 64 + ((dc ^ (kr & 7)) << 3) + dl] =
              (bf16)((acc[mt][nt][r] + bv) * 1.4426950408889634f);
        }
      }
  } else {
    // V: permuted+swizzled 64-key tile image, 4 tokens per bf16x4
#pragma unroll
    for (int mt = 0; mt < 4; ++mt)
      for (int nt = 0; nt < 4; ++nt) {
        const int n = n0 + wn + nt * 16 + l16;
        const float bv = bias[n];
        const int vd = n - 2048, hh = vd >> 6, d = vd & 63;
        const int m = m0 + wm + mt * 16 + quad * 4;
        const int bb = m >> 11, s = m & 2047;
        const int t = s >> 6, kt = s & 63;
        const int g = kt >> 4, w = kt & 15;
        const int c = 2 * g + ((w >> 2) & 1);
        const int slot = (w & 8) ? 4 : 0;
        const size_t base = ((size_t)((bb * 16 + hh) * 32 + t)) * 8192 + 4096;
        bf16x4 pkv;
#pragma unroll
        for (int r = 0; r < 4; ++r) pkv[r] = (bf16)(acc[mt][nt][r] + bv);
        *(bf16x4*)(kv + base + d * 64 + ((c ^ (d & 7)) << 3) + slot) = pkv;
      }
  }
}

// ---------------- GEMM 128x128 ring3+swz: C = A @ W^T + bias --------------
__global__ __launch_bounds__(256) void gemm_bt(
    const bf16* __restrict__ A, const bf16* __restrict__ W,
    const float* __restrict__ bias,
    float* __restrict__ outF, bf16* __restrict__ outB,
    int M, int N, int K, int nbx) {
  __shared__ bf16 Ab[3][4096];
  __shared__ bf16 Bb[3][4096];
  const int tid = threadIdx.x, lane = tid & 63, wave = tid >> 6;
  const int quad = lane >> 4, l16 = lane & 15;
  int bx, by;
  xcd_map(nbx, nbx * (M >> 7), bx, by);
  const int m0 = by * 128, n0 = bx * 128;
  const int wm = (wave >> 1) * 64, wn = (wave & 1) * 64;
  const int srow = wave * 32 + (lane >> 2);
  const int scol = ((lane & 3) ^ ((lane >> 2) & 3)) * 8;
  const bf16* a0 = A + (size_t)(m0 + srow) * K + scol;
  const bf16* a1 = A + (size_t)(m0 + srow + 16) * K + scol;
  const bf16* w0p = W + (size_t)(n0 + srow) * K + scol;
  const bf16* w1p = W + (size_t)(n0 + srow + 16) * K + scol;
  const int sq = (quad ^ (l16 & 3)) * 8;
  const int nit = K >> 5;
#pragma unroll
  for (int t = 0; t < 2; ++t) {
    gll16(a0 + t * 32, Ab[t] + wave * 1024);
    gll16(a1 + t * 32, Ab[t] + wave * 1024 + 512);
    gll16(w0p + t * 32, Bb[t] + wave * 1024);
    gll16(w1p + t * 32, Bb[t] + wave * 1024 + 512);
  }
  f32x4 acc[4][4] = {};
  int rd = 0, wr = 2;
  for (int g = 0; g < nit; ++g) {
    if (g < nit - 1) asm volatile("s_waitcnt vmcnt(4)" ::: "memory");
    else             asm volatile("s_waitcnt vmcnt(0)" ::: "memory");
    __builtin_amdgcn_s_barrier();
    __builtin_amdgcn_sched_barrier(0);
    if (g + 2 < nit) {
      const int k1 = (g + 2) * 32;
      bf16* da = Ab[wr];
      bf16* db = Bb[wr];
      gll16(a0 + k1, da + wave * 1024);
      gll16(a1 + k1, da + wave * 1024 + 512);
      gll16(w0p + k1, db + wave * 1024);
      gll16(w1p + k1, db + wave * 1024 + 512);
    }
    const bf16* As = Ab[rd];
    const bf16* Bs = Bb[rd];
    bf16x8 af[4], bw[4];
#pragma unroll
    for (int t = 0; t < 4; ++t) {
      af[t] = *(const bf16x8*)(As + (wm + t * 16 + l16) * 32 + sq);
      bw[t] = *(const bf16x8*)(Bs + (wn + t * 16 + l16) * 32 + sq);
    }
    __builtin_amdgcn_s_setprio(1);
#pragma unroll
    for (int mt = 0; mt < 4; ++mt)
#pragma unroll
      for (int nt = 0; nt < 4; ++nt)
        acc[mt][nt] = mfma16(af[mt], bw[nt], acc[mt][nt]);
    __builtin_amdgcn_s_setprio(0);
    rd = (rd + 1 == 3) ? 0 : rd + 1;
    wr = (wr + 1 == 3) ? 0 : wr + 1;
  }
#pragma unroll
  for (int mt = 0; mt < 4; ++mt)
    for (int nt = 0; nt < 4; ++nt) {
      const int n = n0 + wn + nt * 16 + l16;
      const float bv = bias ? bias[n] : 0.0f;
#pragma unroll
      for (int r = 0; r < 4; ++r) {
        const int m = m0 + wm + mt * 16 + quad * 4 + r;
        const float v = acc[mt][nt][r] + bv;
        if (outF) outF[(size_t)m * N + n] = v;
        if (outB) outB[(size_t)m * N + n] = (bf16)v;
      }
    }
}

// ---------------- GEMM 128x64 ring3+swz (out-proj) ----------------
__global__ __launch_bounds__(256) void gemm_bt64(
    const bf16* __restrict__ A, const bf16* __restrict__ W,
    const float* __restrict__ bias, float* __restrict__ outF,
    int M, int N, int K) {
  __shared__ bf16 Ab[3][4096];
  __shared__ bf16 Bb[3][2048];
  const int tid = threadIdx.x, lane = tid & 63, wave = tid >> 6;
  const int quad = lane >> 4, l16 = lane & 15;
  int bx, by;
  xcd_map(16, 16 * 32, bx, by);
  const int m0 = by * 128, n0 = bx * 64;
  const int wm = (wave >> 1) * 64, wn = (wave & 1) * 32;
  const int srow = wave * 32 + (lane >> 2);
  const int srowB = wave * 16 + (lane >> 2);
  const int scol = ((lane & 3) ^ ((lane >> 2) & 3)) * 8;
  const bf16* a0 = A + (size_t)(m0 + srow) * K + scol;
  const bf16* a1 = A + (size_t)(m0 + srow + 16) * K + scol;
  const bf16* w0p = W + (size_t)(n0 + srowB) * K + scol;
  const int sq = (quad ^ (l16 & 3)) * 8;
  const int nit = K >> 5;
#pragma unroll
  for (int t = 0; t < 2; ++t) {
    gll16(a0 + t * 32, Ab[t] + wave * 1024);
    gll16(a1 + t * 32, Ab[t] + wave * 1024 + 512);
    gll16(w0p + t * 32, Bb[t] + wave * 512);
  }
  f32x4 acc[4][2] = {};
  int rd = 0, wr = 2;
  for (int g = 0; g < nit; ++g) {
    if (g < nit - 1) asm volatile("s_waitcnt vmcnt(3)" ::: "memory");
    else             asm volatile("s_waitcnt vmcnt(0)" ::: "memory");
    __builtin_amdgcn_s_barrier();
    __builtin_amdgcn_sched_barrier(0);
    if (g + 2 < nit) {
      const int k1 = (g + 2) * 32;
      gll16(a0 + k1, Ab[wr] + wave * 1024);
      gll16(a1 + k1, Ab[wr] + wave * 1024 + 512);
      gll16(w0p + k1, Bb[wr] + wave * 512);
    }
    const bf16* As = Ab[rd];
    const bf16* Bs = Bb[rd];
    bf16x8 af[4], bw[2];
#pragma unroll
    for (int t = 0; t < 4; ++t)
      af[t] = *(const bf16x8*)(As + (wm + t * 16 + l16) * 32 + sq);
#pragma unroll
    for (int t = 0; t < 2; ++t)
      bw[t] = *(const bf16x8*)(Bs + (wn + t * 16 + l16) * 32 + sq);
    __builtin_amdgcn_s_setprio(1);
#pragma unroll
    for (int mt = 0; mt < 4; ++mt)
#pragma unroll
      for (int nt = 0; nt < 2; ++nt)
        acc[mt][nt] = mfma16(af[mt], bw[nt], acc[mt][nt]);
    __builtin_amdgcn_s_setprio(0);
    rd = (rd + 1 == 3) ? 0 : rd + 1;
    wr = (wr + 1 == 3) ? 0 : wr + 1;
  }
#pragma unroll
  for (int mt = 0; mt < 4; ++mt)
    for (int nt = 0; nt < 2; ++nt) {
      const int n = n0 + wn + nt * 16 + l16;
      const float bv = bias[n];
#pragma unroll
      for (int r = 0; r < 4; ++r) {
        const int m = m0 + wm + mt * 16 + quad * 4 + r;
        outF[(size_t)m * N + n] = acc[mt][nt][r] + bv;
      }
    }
}

// ---------------- flash attention v14: dual-stream + counted vmcnt ---------
__global__ __launch_bounds__(256, 2) void attn14(
    const bf16* __restrict__ Q, const bf16* __restrict__ KV,
    bf16* __restrict__ ctx) {
  __shared__ __align__(16) bf16 kvb[2][16384];  // [buf][2 x (K 4096 | V 4096)]
  __shared__ float Linv[4][32];
  const int tid = threadIdx.x, lane = tid & 63, wave = tid >> 6;
  const int hi = lane >> 5, l31 = lane & 31, l7 = lane & 7;
  const int bid = blockIdx.x;
  const int hb = (bid & 7) * 4 + ((bid >> 3) & 3);
  const int qt = bid >> 5;              // 0..15
  const int h = hb & 15, b = hb >> 4;

  bf16x8 qf[4];
  {
    const int qrow = qt * 128 + wave * 32 + l31;
    const bf16* qp = Q + (size_t)(b * SEQ + qrow) * 1024 + h * HD + hi * 8;
#pragma unroll
    for (int t = 0; t < 4; ++t) qf[t] = *(const bf16x8*)(qp + t * 16);
  }
  asm volatile("s_waitcnt vmcnt(0)" ::: "memory");

  const int soff = tid * 8;
  const bf16* kvg = KV + ((size_t)(b * NH + h) * 32) * 8192 + soff;
#pragma unroll
  for (int i = 0; i < 8; ++i)
    gll16(kvg + i * 2048, kvb[0] + soff + i * 2048);
#pragma unroll
  for (int i = 0; i < 8; ++i)
    gll16(kvg + 16384 + i * 2048, kvb[1] + soff + i * 2048);

  f32x16 o0 = {}, o1 = {};
  float lpart = 0.0f;
  const f32x16 zf = {};

  for (int t = 0; t < 16; ++t) {
    if (t < 15) asm volatile("s_waitcnt vmcnt(8)" ::: "memory");
    else        asm volatile("s_waitcnt vmcnt(0)" ::: "memory");
    __builtin_amdgcn_s_barrier();
    __builtin_amdgcn_sched_barrier(0);
    const bf16* tb = kvb[t & 1];
#pragma unroll
    for (int half = 0; half < 2; ++half) {
      const bf16* ks = tb + half * 8192;
      const bf16* vs = ks + 4096;
      f32x16 s0, s1;
      __builtin_amdgcn_s_setprio(1);
      {
        const int swc = (hi ^ l7) * 8;
        bf16x8 k0 = *(const bf16x8*)(ks + l31 * 64 + swc);
        bf16x8 k1 = *(const bf16x8*)(ks + (32 + l31) * 64 + swc);
        s0 = mfma32(k0, qf[0], zf);
        s1 = mfma32(k1, qf[0], zf);
      }
#pragma unroll
      for (int tt = 1; tt < 4; ++tt) {
        const int swc = ((tt * 2 + hi) ^ l7) * 8;
        bf16x8 k0 = *(const bf16x8*)(ks + l31 * 64 + swc);
        bf16x8 k1 = *(const bf16x8*)(ks + (32 + l31) * 64 + swc);
        s0 = mfma32(k0, qf[tt], s0);
        s1 = mfma32(k1, qf[tt], s1);
      }
      __builtin_amdgcn_s_setprio(0);
      unsigned u[16];
#pragma unroll
      for (int g = 0; g < 8; ++g) {
        const int base = (g & 3) * 4;
        float e0, e1, e2, e3;
        if (g < 4) {
          e0 = __builtin_amdgcn_exp2f(s0[base]);
          e1 = __builtin_amdgcn_exp2f(s0[base + 1]);
          e2 = __builtin_amdgcn_exp2f(s0[base + 2]);
          e3 = __builtin_amdgcn_exp2f(s0[base + 3]);
        } else {
          e0 = __builtin_amdgcn_exp2f(s1[base]);
          e1 = __builtin_amdgcn_exp2f(s1[base + 1]);
          e2 = __builtin_amdgcn_exp2f(s1[base + 2]);
          e3 = __builtin_amdgcn_exp2f(s1[base + 3]);
        }
        lpart += (e0 + e1) + (e2 + e3);
        u[g * 2] = pk2(e0, e1);
        u[g * 2 + 1] = pk2(e2, e3);
      }
      __builtin_amdgcn_s_setprio(1);
#pragma unroll
      for (int kk = 0; kk < 4; ++kk) {
        union { unsigned w[4]; bf16x8 v; } fw;
        fw.w[0] = u[4 * kk]; fw.w[1] = u[4 * kk + 1];
        fw.w[2] = u[4 * kk + 2]; fw.w[3] = u[4 * kk + 3];
        const int c16 = (2 * kk + hi) ^ l7;
        bf16x8 v0 = *(const bf16x8*)(vs + l31 * 64 + c16 * 8);
        bf16x8 v1 = *(const bf16x8*)(vs + (32 + l31) * 64 + c16 * 8);
        o0 = mfma32(fw.v, v0, o0);
        o1 = mfma32(fw.v, v1, o1);
      }
      __builtin_amdgcn_s_setprio(0);
    }
    __builtin_amdgcn_sched_barrier(0);
    __builtin_amdgcn_s_barrier();
    __builtin_amdgcn_sched_barrier(0);
    if (t + 2 < 16) {
      const bf16* src = kvg + (size_t)(t + 2) * 16384;
      bf16* dst = kvb[t & 1] + soff;
#pragma unroll
      for (int i = 0; i < 8; ++i) gll16(src + i * 2048, dst + i * 2048);
    }
  }
  float ltot = lpart + __shfl_xor(lpart, 32, 64);
  if (lane < 32) Linv[wave][lane] = 1.0f / ltot;
#pragma unroll
  for (int r = 0; r < 16; ++r) {
    const int qloc = (r & 3) + 8 * (r >> 2) + 4 * hi;
    const float inv = Linv[wave][qloc];
    const int qrow = qt * 128 + wave * 32 + qloc;
    bf16* cp = ctx + (size_t)(b * SEQ + qrow) * EMB + h * HD;
    cp[l31] = (bf16)(o0[r] * inv);
    cp[32 + l31] = (bf16)(o1[r] * inv);
  }
}

// ---------------- residual + LayerNorm ----------------
__global__ __launch_bounds__(256) void ln1_k(
    const float* __restrict__ x, const float* __restrict__ ao,
    const float* __restrict__ g, const float* __restrict__ bta,
    float* __restrict__ hF, bf16* __restrict__ hB) {
  int row = blockIdx.x, tid = threadIdx.x;
  const float* xr = x + (size_t)row * EMB;
  const float* ar = ao + (size_t)row * EMB;
  float v[4], s = 0.0f, s2 = 0.0f;
#pragma unroll
  for (int i = 0; i < 4; ++i) {
    float t = xr[tid + i * 256] + ar[tid + i * 256];
    v[i] = t; s += t; s2 += t * t;
  }
#pragma unroll
  for (int off = 1; off < 64; off <<= 1) {
    s += __shfl_xor(s, off, 64);
    s2 += __shfl_xor(s2, off, 64);
  }
  __shared__ float red[8];
  int wave = tid >> 6, lane = tid & 63;
  if (lane == 0) { red[wave] = s; red[4 + wave] = s2; }
  __syncthreads();
  s = red[0] + red[1] + red[2] + red[3];
  s2 = red[4] + red[5] + red[6] + red[7];
  float mean = s * (1.0f / EMB);
  float var = s2 * (1.0f / EMB) - mean * mean;
  float inv = rsqrtf(var + 1e-5f);
#pragma unroll
  for (int i = 0; i < 4; ++i) {
    int c = tid + i * 256;
    float t = (v[i] - mean) * inv * g[c] + bta[c];
    hF[(size_t)row * EMB + c] = t;
    hB[(size_t)row * EMB + c] = (bf16)t;
  }
}

__global__ __launch_bounds__(256) void geglu_ln2(
    const float* __restrict__ h, const bf16* __restrict__ proj,
    const float* __restrict__ g, const float* __restrict__ bta,
    float* __restrict__ out) {
  int row = blockIdx.x, tid = threadIdx.x;
  const float* hr = h + (size_t)row * EMB;
  const bf16* pr = proj + (size_t)row * 2048;
  float v[4], s = 0.0f, s2 = 0.0f;
#pragma unroll
  for (int i = 0; i < 4; ++i) {
    int c = tid + i * 256;
    float val = (float)pr[c];
    float gate = (float)pr[1024 + c];
    float ge = 0.5f * gate * (1.0f + erff(gate * 0.70710678f));
    float t = hr[c] + val * ge;
    v[i] = t; s += t; s2 += t * t;
  }
#pragma unroll
  for (int off = 1; off < 64; off <<= 1) {
    s += __shfl_xor(s, off, 64);
    s2 += __shfl_xor(s2, off, 64);
  }
  __shared__ float red[8];
  int wave = tid >> 6, lane = tid & 63;
  if (lane == 0) { red[wave] = s; red[4 + wave] = s2; }
  __syncthreads();
  s = red[0] + red[1] + red[2] + red[3];
  s2 = red[4] + red[5] + red[6] + red[7];
  float mean = s * (1.0f / EMB);
  float var = s2 * (1.0f / EMB) - mean * mean;
  float inv = rsqrtf(var + 1e-5f);
#pragma unroll
  for (int i = 0; i < 4; ++i) {
    int c = tid + i * 256;
    out[(size_t)row * EMB + c] = (v[i] - mean) * inv * g[c] + bta[c];
  }
}

extern "C" void kernel_launch(void* const* d_in, const int* in_sizes, int n_in,
                              void* d_out, int out_size, void* d_ws, size_t ws_size,
                              hipStream_t stream) {
  const float* x = (const float*)d_in[0];
  const float* inW = (const float*)d_in[1];
  const float* inB = (const float*)d_in[2];
  const float* outW = (const float*)d_in[3];
  const float* opB = (const float*)d_in[4];
  const float* ggW = (const float*)d_in[5];
  const float* ggB = (const float*)d_in[6];
  const float* g1 = (const float*)d_in[7];
  const float* b1 = (const float*)d_in[8];
  const float* g2 = (const float*)d_in[9];
  const float* b2 = (const float*)d_in[10];
  float* out = (float*)d_out;
  char* ws = (char*)d_ws;
  const size_t MB = 1ull << 20;
  bf16* xb = (bf16*)(ws);              // 8 MB, dead after gemm_in
  bf16* hB = (bf16*)(ws);              // overlays xb (ln1 out)
  bf16* qr = (bf16*)(ws + 8 * MB);     // 8 MB, dead after gemm_in
  bf16* ctx = (bf16*)(ws + 8 * MB);    // overlays qr (attn output)
  bf16* wI = (bf16*)(ws + 16 * MB);    // 6 MB
  bf16* wO = (bf16*)(ws + 22 * MB);    // 2 MB
  bf16* wG = (bf16*)(ws + 24 * MB);    // 4 MB
  bf16* qb = (bf16*)(ws + 28 * MB);    // 8 MB, dead after attn
  bf16* kv = (bf16*)(ws + 36 * MB);    // 16 MB tile images, dead after attn
  bf16* projB = (bf16*)(ws + 28 * MB); // overlays qb+kv (GeGLU proj)
  float* ao = (float*)(ws + 52 * MB);  // 16 MB f32

  prep_all<<<8192 + 6144, 256, 0, stream>>>(x, xb, qr, inW, outW, ggW,
                                            wI, wO, wG);
  gemm_in<<<dim3(24, 32), 256, 0, stream>>>(qr, xb, wI, inB, qb, kv);
  attn14<<<512, 256, 0, stream>>>(qb, kv, ctx);
  gemm_bt64<<<dim3(16, 32), 256, 0, stream>>>(ctx, wO, opB, ao,
                                              NTOK, 1024, 1024);
  ln1_k<<<NTOK, 256, 0, stream>>>(x, ao, g1, b1, ao, hB);
  gemm_bt<<<dim3(16, 32), 256, 0, stream>>>(hB, wG, ggB, nullptr, projB,
                                            NTOK, 2048, 1024, 16);
  geglu_ln2<<<NTOK, 256, 0, stream>>>(ao, projB, g2, b2, out);
}

// Round 11
// 257.772 us; speedup vs baseline: 1.0374x; 1.0374x over previous
//
#include <hip/hip_runtime.h>

// TransformerBlock on MI355X (gfx950).
// v20: clean BK=64 retest for gemm_in. v19's BK=64 regression was confounded:
// its [128][64] layout tripled bank conflicts (3.1M->9.4M, stride-128B rows).
// v20 keeps the EXACT v14 structure and v14 [128][32] fragment layout but
// stages TWO half-tiles (As0/As1, Bs0/Bs1, 32KB) per __syncthreads pair:
// 16 barrier drains instead of 32, 2x compute per drain, zero addressing
// change -> conflicts stay at v14's level. Everything else = v18 (263.8us).

typedef __bf16 bf16;
typedef bf16 bf16x8 __attribute__((ext_vector_type(8)));
typedef bf16 bf16x4 __attribute__((ext_vector_type(4)));
typedef float f32x4 __attribute__((ext_vector_type(4)));
typedef float f32x16 __attribute__((ext_vector_type(16)));

#define EMB 1024
#define SEQ 2048
#define NTOK 4096
#define NH 16
#define HD 64

__device__ __forceinline__ f32x4 mfma16(bf16x8 a, bf16x8 b, f32x4 c) {
  return __builtin_amdgcn_mfma_f32_16x16x32_bf16(a, b, c, 0, 0, 0);
}
__device__ __forceinline__ f32x16 mfma32(bf16x8 a, bf16x8 b, f32x16 c) {
  return __builtin_amdgcn_mfma_f32_32x32x16_bf16(a, b, c, 0, 0, 0);
}

__device__ __forceinline__ void gll16(const void* g, void* l) {
  __builtin_amdgcn_global_load_lds(
      (const __attribute__((address_space(1))) void*)g,
      (__attribute__((address_space(3))) void*)l, 16, 0, 0);
}

__device__ __forceinline__ unsigned pk2(float a, float b) {
  union { bf16 h[2]; unsigned u; } t;
  t.h[0] = (bf16)a; t.h[1] = (bf16)b;
  return t.u;
}

// XCD-chunked swizzle (nwg % 8 == 0): each XCD gets a contiguous work chunk.
__device__ __forceinline__ void xcd_map(int nx, int nwg, int& bx, int& by) {
  const int lin = blockIdx.y * nx + blockIdx.x;
  const int id = (lin & 7) * (nwg >> 3) + (lin >> 3);
  bx = id % nx;
  by = id / nx;
}

// ---------------- fused elementwise prep (rope+cast, one launch) ----------
__global__ __launch_bounds__(256) void prep_all(
    const float* __restrict__ x, bf16* __restrict__ xb, bf16* __restrict__ qr,
    const float* __restrict__ w0, const float* __restrict__ w1,
    const float* __restrict__ w2, bf16* __restrict__ o0,
    bf16* __restrict__ o1, bf16* __restrict__ o2) {
  const int bid = blockIdx.x;
  if (bid < 8192) {
    int idx = bid * 256 + threadIdx.x;
    int row = idx >> 9;
    int i = idx & 511;
    int h = i >> 5, d2 = i & 31;
    int pos = row & (SEQ - 1);
    int c0 = h * HD + d2;
    size_t base = (size_t)row * EMB;
    float x0 = x[base + c0], x1 = x[base + c0 + 32];
    float invf = exp2f(-(float)d2 * 0.4152410118609203f);
    float ang = (float)pos * invf;
    float sn, cs;
    sincosf(ang, &sn, &cs);
    qr[base + c0] = (bf16)(x0 * cs - x1 * sn);
    qr[base + c0 + 32] = (bf16)(x1 * cs + x0 * sn);
    xb[base + c0] = (bf16)x0;
    xb[base + c0 + 32] = (bf16)x1;
  } else {
    int i = ((bid - 8192) * 256 + threadIdx.x) * 4;
    const float* s; bf16* d; int off;
    if (i < 3 * 1024 * 1024) { s = w0; d = o0; off = i; }
    else if (i < 4 * 1024 * 1024) { s = w1; d = o1; off = i - 3 * 1024 * 1024; }
    else { s = w2; d = o2; off = i - 4 * 1024 * 1024; }
    float4 f = *(const float4*)(s + off);
    d[off] = (bf16)f.x; d[off + 1] = (bf16)f.y;
    d[off + 2] = (bf16)f.z; d[off + 3] = (bf16)f.w;
  }
}

// ---------------- fused in-proj GEMM (v14 layout, split-half BK=64) -------
// Outputs: qb[token][1024] pre-scaled by 0.125; kv images per (b,h): 32 tiles
// of 64 keys {K 4096 | V 4096} in the attention LDS layout (K scaled log2e).
__global__ __launch_bounds__(256) void gemm_in(
    const bf16* __restrict__ Aq, const bf16* __restrict__ Ax,
    const bf16* __restrict__ W, const float* __restrict__ bias,
    bf16* __restrict__ qb, bf16* __restrict__ kv) {
  __shared__ bf16 As0[128 * 32], As1[128 * 32];
  __shared__ bf16 Bs0[128 * 32], Bs1[128 * 32];
  const int tid = threadIdx.x, lane = tid & 63, wave = tid >> 6;
  const int quad = lane >> 4, l16 = lane & 15;
  const int m0 = blockIdx.y * 128, n0 = blockIdx.x * 128;
  const bf16* A = (n0 < 2048) ? Aq : Ax;
  const int K = 1024;
  const int wm = (wave >> 1) * 64, wn = (wave & 1) * 64;
  const int srow = wave * 32 + (lane >> 2);
  const int scol = (lane & 3) * 8;
  const bf16* a0 = A + (size_t)(m0 + srow) * K + scol;
  const bf16* a1 = A + (size_t)(m0 + srow + 16) * K + scol;
  const bf16* w0p = W + (size_t)(n0 + srow) * K + scol;
  const bf16* w1p = W + (size_t)(n0 + srow + 16) * K + scol;
  f32x4 acc[4][4] = {};
  for (int k0 = 0; k0 < K; k0 += 64) {
    __syncthreads();
    gll16(a0 + k0, As0 + wave * 1024);
    gll16(a1 + k0, As0 + wave * 1024 + 512);
    gll16(w0p + k0, Bs0 + wave * 1024);
    gll16(w1p + k0, Bs0 + wave * 1024 + 512);
    gll16(a0 + k0 + 32, As1 + wave * 1024);
    gll16(a1 + k0 + 32, As1 + wave * 1024 + 512);
    gll16(w0p + k0 + 32, Bs1 + wave * 1024);
    gll16(w1p + k0 + 32, Bs1 + wave * 1024 + 512);
    __syncthreads();
    {
      bf16x8 af[4], bw[4];
#pragma unroll
      for (int t = 0; t < 4; ++t) {
        af[t] = *(const bf16x8*)(As0 + (wm + t * 16 + l16) * 32 + quad * 8);
        bw[t] = *(const bf16x8*)(Bs0 + (wn + t * 16 + l16) * 32 + quad * 8);
      }
#pragma unroll
      for (int mt = 0; mt < 4; ++mt)
#pragma unroll
        for (int nt = 0; nt < 4; ++nt)
          acc[mt][nt] = mfma16(af[mt], bw[nt], acc[mt][nt]);
    }
    {
      bf16x8 af[4], bw[4];
#pragma unroll
      for (int t = 0; t < 4; ++t) {
        af[t] = *(const bf16x8*)(As1 + (wm + t * 16 + l16) * 32 + quad * 8);
        bw[t] = *(const bf16x8*)(Bs1 + (wn + t * 16 + l16) * 32 + quad * 8);
      }
#pragma unroll
      for (int mt = 0; mt < 4; ++mt)
#pragma unroll
        for (int nt = 0; nt < 4; ++nt)
          acc[mt][nt] = mfma16(af[mt], bw[nt], acc[mt][nt]);
    }
  }
  if (n0 < 1024) {
    // Q: scale 1/8 (exact in bf16)
#pragma unroll
    for (int mt = 0; mt < 4; ++mt)
      for (int nt = 0; nt < 4; ++nt) {
        const int n = n0 + wn + nt * 16 + l16;
        const float bv = bias[n];
#pragma unroll
        for (int r = 0; r < 4; ++r) {
          const int m = m0 + wm + mt * 16 + quad * 4 + r;
          qb[(size_t)m * 1024 + n] = (bf16)((acc[mt][nt][r] + bv) * 0.125f);
        }
      }
  } else if (n0 < 2048) {
    // K: scale log2(e), write into swizzled 64-key tile image
#pragma unroll
    for (int mt = 0; mt < 4; ++mt)
      for (int nt = 0; nt < 4; ++nt) {
        const int n = n0 + wn + nt * 16 + l16;
        const float bv = bias[n];
        const int kd = n - 1024, hh = kd >> 6, d = kd & 63;
        const int dc = d >> 3, dl = d & 7;
#pragma unroll
        for (int r = 0; r < 4; ++r) {
          const int m = m0 + wm + mt * 16 + quad * 4 + r;
          const int bb = m >> 11, s = m & 2047;
          const int t = s >> 6, kr = s & 63;
          const size_t base = ((size_t)((bb * 16 + hh) * 32 + t)) * 8192;
          kv[base + kr * 64 + ((dc ^ (kr & 7)) << 3) + dl] =
              (bf16)((acc[mt][nt][r] + bv) * 1.4426950408889634f);
        }
      }
  } else {
    // V: permuted+swizzled 64-key tile image, 4 tokens per bf16x4
#pragma unroll
    for (int mt = 0; mt < 4; ++mt)
      for (int nt = 0; nt < 4; ++nt) {
        const int n = n0 + wn + nt * 16 + l16;
        const float bv = bias[n];
        const int vd = n - 2048, hh = vd >> 6, d = vd & 63;
        const int m = m0 + wm + mt * 16 + quad * 4;
        const int bb = m >> 11, s = m & 2047;
        const int t = s >> 6, kt = s & 63;
        const int g = kt >> 4, w = kt & 15;
        const int c = 2 * g + ((w >> 2) & 1);
        const int slot = (w & 8) ? 4 : 0;
        const size_t base = ((size_t)((bb * 16 + hh) * 32 + t)) * 8192 + 4096;
        bf16x4 pkv;
#pragma unroll
        for (int r = 0; r < 4; ++r) pkv[r] = (bf16)(acc[mt][nt][r] + bv);
        *(bf16x4*)(kv + base + d * 64 + ((c ^ (d & 7)) << 3) + slot) = pkv;
      }
  }
}

// ---------------- GEMM 128x128 ring3+swz: C = A @ W^T + bias --------------
__global__ __launch_bounds__(256) void gemm_bt(
    const bf16* __restrict__ A, const bf16* __restrict__ W,
    const float* __restrict__ bias,
    float* __restrict__ outF, bf16* __restrict__ outB,
    int M, int N, int K, int nbx) {
  __shared__ bf16 Ab[3][4096];
  __shared__ bf16 Bb[3][4096];
  const int tid = threadIdx.x, lane = tid & 63, wave = tid >> 6;
  const int quad = lane >> 4, l16 = lane & 15;
  int bx, by;
  xcd_map(nbx, nbx * (M >> 7), bx, by);
  const int m0 = by * 128, n0 = bx * 128;
  const int wm = (wave >> 1) * 64, wn = (wave & 1) * 64;
  const int srow = wave * 32 + (lane >> 2);
  const int scol = ((lane & 3) ^ ((lane >> 2) & 3)) * 8;
  const bf16* a0 = A + (size_t)(m0 + srow) * K + scol;
  const bf16* a1 = A + (size_t)(m0 + srow + 16) * K + scol;
  const bf16* w0p = W + (size_t)(n0 + srow) * K + scol;
  const bf16* w1p = W + (size_t)(n0 + srow + 16) * K + scol;
  const int sq = (quad ^ (l16 & 3)) * 8;
  const int nit = K >> 5;
#pragma unroll
  for (int t = 0; t < 2; ++t) {
    gll16(a0 + t * 32, Ab[t] + wave * 1024);
    gll16(a1 + t * 32, Ab[t] + wave * 1024 + 512);
    gll16(w0p + t * 32, Bb[t] + wave * 1024);
    gll16(w1p + t * 32, Bb[t] + wave * 1024 + 512);
  }
  f32x4 acc[4][4] = {};
  int rd = 0, wr = 2;
  for (int g = 0; g < nit; ++g) {
    if (g < nit - 1) asm volatile("s_waitcnt vmcnt(4)" ::: "memory");
    else             asm volatile("s_waitcnt vmcnt(0)" ::: "memory");
    __builtin_amdgcn_s_barrier();
    __builtin_amdgcn_sched_barrier(0);
    if (g + 2 < nit) {
      const int k1 = (g + 2) * 32;
      bf16* da = Ab[wr];
      bf16* db = Bb[wr];
      gll16(a0 + k1, da + wave * 1024);
      gll16(a1 + k1, da + wave * 1024 + 512);
      gll16(w0p + k1, db + wave * 1024);
      gll16(w1p + k1, db + wave * 1024 + 512);
    }
    const bf16* As = Ab[rd];
    const bf16* Bs = Bb[rd];
    bf16x8 af[4], bw[4];
#pragma unroll
    for (int t = 0; t < 4; ++t) {
      af[t] = *(const bf16x8*)(As + (wm + t * 16 + l16) * 32 + sq);
      bw[t] = *(const bf16x8*)(Bs + (wn + t * 16 + l16) * 32 + sq);
    }
    __builtin_amdgcn_s_setprio(1);
#pragma unroll
    for (int mt = 0; mt < 4; ++mt)
#pragma unroll
      for (int nt = 0; nt < 4; ++nt)
        acc[mt][nt] = mfma16(af[mt], bw[nt], acc[mt][nt]);
    __builtin_amdgcn_s_setprio(0);
    rd = (rd + 1 == 3) ? 0 : rd + 1;
    wr = (wr + 1 == 3) ? 0 : wr + 1;
  }
#pragma unroll
  for (int mt = 0; mt < 4; ++mt)
    for (int nt = 0; nt < 4; ++nt) {
      const int n = n0 + wn + nt * 16 + l16;
      const float bv = bias ? bias[n] : 0.0f;
#pragma unroll
      for (int r = 0; r < 4; ++r) {
        const int m = m0 + wm + mt * 16 + quad * 4 + r;
        const float v = acc[mt][nt][r] + bv;
        if (outF) outF[(size_t)m * N + n] = v;
        if (outB) outB[(size_t)m * N + n] = (bf16)v;
      }
    }
}

// ---------------- GEMM 128x64 ring3+swz (out-proj) ----------------
__global__ __launch_bounds__(256) void gemm_bt64(
    const bf16* __restrict__ A, const bf16* __restrict__ W,
    const float* __restrict__ bias, float* __restrict__ outF,
    int M, int N, int K) {
  __shared__ bf16 Ab[3][4096];
  __shared__ bf16 Bb[3][2048];
  const int tid = threadIdx.x, lane = tid & 63, wave = tid >> 6;
  const int quad = lane >> 4, l16 = lane & 15;
  int bx, by;
  xcd_map(16, 16 * 32, bx, by);
  const int m0 = by * 128, n0 = bx * 64;
  const int wm = (wave >> 1) * 64, wn = (wave & 1) * 32;
  const int srow = wave * 32 + (lane >> 2);
  const int srowB = wave * 16 + (lane >> 2);
  const int scol = ((lane & 3) ^ ((lane >> 2) & 3)) * 8;
  const bf16* a0 = A + (size_t)(m0 + srow) * K + scol;
  const bf16* a1 = A + (size_t)(m0 + srow + 16) * K + scol;
  const bf16* w0p = W + (size_t)(n0 + srowB) * K + scol;
  const int sq = (quad ^ (l16 & 3)) * 8;
  const int nit = K >> 5;
#pragma unroll
  for (int t = 0; t < 2; ++t) {
    gll16(a0 + t * 32, Ab[t] + wave * 1024);
    gll16(a1 + t * 32, Ab[t] + wave * 1024 + 512);
    gll16(w0p + t * 32, Bb[t] + wave * 512);
  }
  f32x4 acc[4][2] = {};
  int rd = 0, wr = 2;
  for (int g = 0; g < nit; ++g) {
    if (g < nit - 1) asm volatile("s_waitcnt vmcnt(3)" ::: "memory");
    else             asm volatile("s_waitcnt vmcnt(0)" ::: "memory");
    __builtin_amdgcn_s_barrier();
    __builtin_amdgcn_sched_barrier(0);
    if (g + 2 < nit) {
      const int k1 = (g + 2) * 32;
      gll16(a0 + k1, Ab[wr] + wave * 1024);
      gll16(a1 + k1, Ab[wr] + wave * 1024 + 512);
      gll16(w0p + k1, Bb[wr] + wave * 512);
    }
    const bf16* As = Ab[rd];
    const bf16* Bs = Bb[rd];
    bf16x8 af[4], bw[2];
#pragma unroll
    for (int t = 0; t < 4; ++t)
      af[t] = *(const bf16x8*)(As + (wm + t * 16 + l16) * 32 + sq);
#pragma unroll
    for (int t = 0; t < 2; ++t)
      bw[t] = *(const bf16x8*)(Bs + (wn + t * 16 + l16) * 32 + sq);
    __builtin_amdgcn_s_setprio(1);
#pragma unroll
    for (int mt = 0; mt < 4; ++mt)
#pragma unroll
      for (int nt = 0; nt < 2; ++nt)
        acc[mt][nt] = mfma16(af[mt], bw[nt], acc[mt][nt]);
    __builtin_amdgcn_s_setprio(0);
    rd = (rd + 1 == 3) ? 0 : rd + 1;
    wr = (wr + 1 == 3) ? 0 : wr + 1;
  }
#pragma unroll
  for (int mt = 0; mt < 4; ++mt)
    for (int nt = 0; nt < 2; ++nt) {
      const int n = n0 + wn + nt * 16 + l16;
      const float bv = bias[n];
#pragma unroll
      for (int r = 0; r < 4; ++r) {
        const int m = m0 + wm + mt * 16 + quad * 4 + r;
        outF[(size_t)m * N + n] = acc[mt][nt][r] + bv;
      }
    }
}

// ---------------- flash attention v14: dual-stream + counted vmcnt ---------
__global__ __launch_bounds__(256, 2) void attn14(
    const bf16* __restrict__ Q, const bf16* __restrict__ KV,
    bf16* __restrict__ ctx) {
  __shared__ __align__(16) bf16 kvb[2][16384];  // [buf][2 x (K 4096 | V 4096)]
  __shared__ float Linv[4][32];
  const int tid = threadIdx.x, lane = tid & 63, wave = tid >> 6;
  const int hi = lane >> 5, l31 = lane & 31, l7 = lane & 7;
  const int bid = blockIdx.x;
  const int hb = (bid & 7) * 4 + ((bid >> 3) & 3);
  const int qt = bid >> 5;              // 0..15
  const int h = hb & 15, b = hb >> 4;

  bf16x8 qf[4];
  {
    const int qrow = qt * 128 + wave * 32 + l31;
    const bf16* qp = Q + (size_t)(b * SEQ + qrow) * 1024 + h * HD + hi * 8;
#pragma unroll
    for (int t = 0; t < 4; ++t) qf[t] = *(const bf16x8*)(qp + t * 16);
  }
  asm volatile("s_waitcnt vmcnt(0)" ::: "memory");

  const int soff = tid * 8;
  const bf16* kvg = KV + ((size_t)(b * NH + h) * 32) * 8192 + soff;
#pragma unroll
  for (int i = 0; i < 8; ++i)
    gll16(kvg + i * 2048, kvb[0] + soff + i * 2048);
#pragma unroll
  for (int i = 0; i < 8; ++i)
    gll16(kvg + 16384 + i * 2048, kvb[1] + soff + i * 2048);

  f32x16 o0 = {}, o1 = {};
  float lpart = 0.0f;
  const f32x16 zf = {};

  for (int t = 0; t < 16; ++t) {
    if (t < 15) asm volatile("s_waitcnt vmcnt(8)" ::: "memory");
    else        asm volatile("s_waitcnt vmcnt(0)" ::: "memory");
    __builtin_amdgcn_s_barrier();
    __builtin_amdgcn_sched_barrier(0);
    const bf16* tb = kvb[t & 1];
#pragma unroll
    for (int half = 0; half < 2; ++half) {
      const bf16* ks = tb + half * 8192;
      const bf16* vs = ks + 4096;
      f32x16 s0, s1;
      __builtin_amdgcn_s_setprio(1);
      {
        const int swc = (hi ^ l7) * 8;
        bf16x8 k0 = *(const bf16x8*)(ks + l31 * 64 + swc);
        bf16x8 k1 = *(const bf16x8*)(ks + (32 + l31) * 64 + swc);
        s0 = mfma32(k0, qf[0], zf);
        s1 = mfma32(k1, qf[0], zf);
      }
#pragma unroll
      for (int tt = 1; tt < 4; ++tt) {
        const int swc = ((tt * 2 + hi) ^ l7) * 8;
        bf16x8 k0 = *(const bf16x8*)(ks + l31 * 64 + swc);
        bf16x8 k1 = *(const bf16x8*)(ks + (32 + l31) * 64 + swc);
        s0 = mfma32(k0, qf[tt], s0);
        s1 = mfma32(k1, qf[tt], s1);
      }
      __builtin_amdgcn_s_setprio(0);
      unsigned u[16];
#pragma unroll
      for (int g = 0; g < 8; ++g) {
        const int base = (g & 3) * 4;
        float e0, e1, e2, e3;
        if (g < 4) {
          e0 = __builtin_amdgcn_exp2f(s0[base]);
          e1 = __builtin_amdgcn_exp2f(s0[base + 1]);
          e2 = __builtin_amdgcn_exp2f(s0[base + 2]);
          e3 = __builtin_amdgcn_exp2f(s0[base + 3]);
        } else {
          e0 = __builtin_amdgcn_exp2f(s1[base]);
          e1 = __builtin_amdgcn_exp2f(s1[base + 1]);
          e2 = __builtin_amdgcn_exp2f(s1[base + 2]);
          e3 = __builtin_amdgcn_exp2f(s1[base + 3]);
        }
        lpart += (e0 + e1) + (e2 + e3);
        u[g * 2] = pk2(e0, e1);
        u[g * 2 + 1] = pk2(e2, e3);
      }
      __builtin_amdgcn_s_setprio(1);
#pragma unroll
      for (int kk = 0; kk < 4; ++kk) {
        union { unsigned w[4]; bf16x8 v; } fw;
        fw.w[0] = u[4 * kk]; fw.w[1] = u[4 * kk + 1];
        fw.w[2] = u[4 * kk + 2]; fw.w[3] = u[4 * kk + 3];
        const int c16 = (2 * kk + hi) ^ l7;
        bf16x8 v0 = *(const bf16x8*)(vs + l31 * 64 + c16 * 8);
        bf16x8 v1 = *(const bf16x8*)(vs + (32 + l31) * 64 + c16 * 8);
        o0 = mfma32(fw.v, v0, o0);
        o1 = mfma32(fw.v, v1, o1);
      }
      __builtin_amdgcn_s_setprio(0);
    }
    __builtin_amdgcn_sched_barrier(0);
    __builtin_amdgcn_s_barrier();
    __builtin_amdgcn_sched_barrier(0);
    if (t + 2 < 16) {
      const bf16* src = kvg + (size_t)(t + 2) * 16384;
      bf16* dst = kvb[t & 1] + soff;
#pragma unroll
      for (int i = 0; i < 8; ++i) gll16(src + i * 2048, dst + i * 2048);
    }
  }
  float ltot = lpart + __shfl_xor(lpart, 32, 64);
  if (lane < 32) Linv[wave][lane] = 1.0f / ltot;
#pragma unroll
  for (int r = 0; r < 16; ++r) {
    const int qloc = (r & 3) + 8 * (r >> 2) + 4 * hi;
    const float inv = Linv[wave][qloc];
    const int qrow = qt * 128 + wave * 32 + qloc;
    bf16* cp = ctx + (size_t)(b * SEQ + qrow) * EMB + h * HD;
    cp[l31] = (bf16)(o0[r] * inv);
    cp[32 + l31] = (bf16)(o1[r] * inv);
  }
}

// ---------------- residual + LayerNorm ----------------
__global__ __launch_bounds__(256) void ln1_k(
    const float* __restrict__ x, const float* __restrict__ ao,
    const float* __restrict__ g, const float* __restrict__ bta,
    float* __restrict__ hF, bf16* __restrict__ hB) {
  int row = blockIdx.x, tid = threadIdx.x;
  const float* xr = x + (size_t)row * EMB;
  const float* ar = ao + (size_t)row * EMB;
  float v[4], s = 0.0f, s2 = 0.0f;
#pragma unroll
  for (int i = 0; i < 4; ++i) {
    float t = xr[tid + i * 256] + ar[tid + i * 256];
    v[i] = t; s += t; s2 += t * t;
  }
#pragma unroll
  for (int off = 1; off < 64; off <<= 1) {
    s += __shfl_xor(s, off, 64);
    s2 += __shfl_xor(s2, off, 64);
  }
  __shared__ float red[8];
  int wave = tid >> 6, lane = tid & 63;
  if (lane == 0) { red[wave] = s; red[4 + wave] = s2; }
  __syncthreads();
  s = red[0] + red[1] + red[2] + red[3];
  s2 = red[4] + red[5] + red[6] + red[7];
  float mean = s * (1.0f / EMB);
  float var = s2 * (1.0f / EMB) - mean * mean;
  float inv = rsqrtf(var + 1e-5f);
#pragma unroll
  for (int i = 0; i < 4; ++i) {
    int c = tid + i * 256;
    float t = (v[i] - mean) * inv * g[c] + bta[c];
    hF[(size_t)row * EMB + c] = t;
    hB[(size_t)row * EMB + c] = (bf16)t;
  }
}

__global__ __launch_bounds__(256) void geglu_ln2(
    const float* __restrict__ h, const bf16* __restrict__ proj,
    const float* __restrict__ g, const float* __restrict__ bta,
    float* __restrict__ out) {
  int row = blockIdx.x, tid = threadIdx.x;
  const float* hr = h + (size_t)row * EMB;
  const bf16* pr = proj + (size_t)row * 2048;
  float v[4], s = 0.0f, s2 = 0.0f;
#pragma unroll
  for (int i = 0; i < 4; ++i) {
    int c = tid + i * 256;
    float val = (float)pr[c];
    float gate = (float)pr[1024 + c];
    float ge = 0.5f * gate * (1.0f + erff(gate * 0.70710678f));
    float t = hr[c] + val * ge;
    v[i] = t; s += t; s2 += t * t;
  }
#pragma unroll
  for (int off = 1; off < 64; off <<= 1) {
    s += __shfl_xor(s, off, 64);
    s2 += __shfl_xor(s2, off, 64);
  }
  __shared__ float red[8];
  int wave = tid >> 6, lane = tid & 63;
  if (lane == 0) { red[wave] = s; red[4 + wave] = s2; }
  __syncthreads();
  s = red[0] + red[1] + red[2] + red[3];
  s2 = red[4] + red[5] + red[6] + red[7];
  float mean = s * (1.0f / EMB);
  float var = s2 * (1.0f / EMB) - mean * mean;
  float inv = rsqrtf(var + 1e-5f);
#pragma unroll
  for (int i = 0; i < 4; ++i) {
    int c = tid + i * 256;
    out[(size_t)row * EMB + c] = (v[i] - mean) * inv * g[c] + bta[c];
  }
}

extern "C" void kernel_launch(void* const* d_in, const int* in_sizes, int n_in,
                              void* d_out, int out_size, void* d_ws, size_t ws_size,
                              hipStream_t stream) {
  const float* x = (const float*)d_in[0];
  const float* inW = (const float*)d_in[1];
  const float* inB = (const float*)d_in[2];
  const float* outW = (const float*)d_in[3];
  const float* opB = (const float*)d_in[4];
  const float* ggW = (const float*)d_in[5];
  const float* ggB = (const float*)d_in[6];
  const float* g1 = (const float*)d_in[7];
  const float* b1 = (const float*)d_in[8];
  const float* g2 = (const float*)d_in[9];
  const float* b2 = (const float*)d_in[10];
  float* out = (float*)d_out;
  char* ws = (char*)d_ws;
  const size_t MB = 1ull << 20;
  bf16* xb = (bf16*)(ws);              // 8 MB, dead after gemm_in
  bf16* hB = (bf16*)(ws);              // overlays xb (ln1 out)
  bf16* qr = (bf16*)(ws + 8 * MB);     // 8 MB, dead after gemm_in
  bf16* ctx = (bf16*)(ws + 8 * MB);    // overlays qr (attn output)
  bf16* wI = (bf16*)(ws + 16 * MB);    // 6 MB
  bf16* wO = (bf16*)(ws + 22 * MB);    // 2 MB
  bf16* wG = (bf16*)(ws + 24 * MB);    // 4 MB
  bf16* qb = (bf16*)(ws + 28 * MB);    // 8 MB, dead after attn
  bf16* kv = (bf16*)(ws + 36 * MB);    // 16 MB tile images, dead after attn
  bf16* projB = (bf16*)(ws + 28 * MB); // overlays qb+kv (GeGLU proj)
  float* ao = (float*)(ws + 52 * MB);  // 16 MB f32

  prep_all<<<8192 + 6144, 256, 0, stream>>>(x, xb, qr, inW, outW, ggW,
                                            wI, wO, wG);
  gemm_in<<<dim3(24, 32), 256, 0, stream>>>(qr, xb, wI, inB, qb, kv);
  attn14<<<512, 256, 0, stream>>>(qb, kv, ctx);
  gemm_bt64<<<dim3(16, 32), 256, 0, stream>>>(ctx, wO, opB, ao,
                                              NTOK, 1024, 1024);
  ln1_k<<<NTOK, 256, 0, stream>>>(x, ao, g1, b1, ao, hB);
  gemm_bt<<<dim3(16, 32), 256, 0, stream>>>(hB, wG, ggB, nullptr, projB,
                                            NTOK, 2048, 1024, 16);
  geglu_ln2<<<NTOK, 256, 0, stream>>>(ao, projB, g2, b2, out);
}

// Round 12
// 257.527 us; speedup vs baseline: 1.0384x; 1.0010x over previous
//
#include <hip/hip_runtime.h>

// TransformerBlock on MI355X (gfx950).
// v21: propagate the measured-best GEMM structure (v20 split-half BK=64:
// single __syncthreads pair per 64-wide K-step, two half-tiles, v14 [128][32]
// layout, plain grid, compiler-scheduled) from gemm_in to gemm_bt (GeGLU) and
// gemm_bt64 (out-proj), replacing ring3+swz. Structure ranking measured over
// v14-v20: split-half > simple > dbuf > ring3+swz > 4ring. Also prep_all RoPE
// sincosf -> v_sin/v_cos via revolutions+fract (err ~2.4e-4 rad << bf16 ulp).
// attn14, gemm_in(v20), LNs unchanged.

typedef __bf16 bf16;
typedef bf16 bf16x8 __attribute__((ext_vector_type(8)));
typedef bf16 bf16x4 __attribute__((ext_vector_type(4)));
typedef float f32x4 __attribute__((ext_vector_type(4)));
typedef float f32x16 __attribute__((ext_vector_type(16)));

#define EMB 1024
#define SEQ 2048
#define NTOK 4096
#define NH 16
#define HD 64

__device__ __forceinline__ f32x4 mfma16(bf16x8 a, bf16x8 b, f32x4 c) {
  return __builtin_amdgcn_mfma_f32_16x16x32_bf16(a, b, c, 0, 0, 0);
}
__device__ __forceinline__ f32x16 mfma32(bf16x8 a, bf16x8 b, f32x16 c) {
  return __builtin_amdgcn_mfma_f32_32x32x16_bf16(a, b, c, 0, 0, 0);
}

__device__ __forceinline__ void gll16(const void* g, void* l) {
  __builtin_amdgcn_global_load_lds(
      (const __attribute__((address_space(1))) void*)g,
      (__attribute__((address_space(3))) void*)l, 16, 0, 0);
}

__device__ __forceinline__ unsigned pk2(float a, float b) {
  union { bf16 h[2]; unsigned u; } t;
  t.h[0] = (bf16)a; t.h[1] = (bf16)b;
  return t.u;
}

// ---------------- fused elementwise prep (rope+cast, one launch) ----------
__global__ __launch_bounds__(256) void prep_all(
    const float* __restrict__ x, bf16* __restrict__ xb, bf16* __restrict__ qr,
    const float* __restrict__ w0, const float* __restrict__ w1,
    const float* __restrict__ w2, bf16* __restrict__ o0,
    bf16* __restrict__ o1, bf16* __restrict__ o2) {
  const int bid = blockIdx.x;
  if (bid < 8192) {
    int idx = bid * 256 + threadIdx.x;
    int row = idx >> 9;
    int i = idx & 511;
    int h = i >> 5, d2 = i & 31;
    int pos = row & (SEQ - 1);
    int c0 = h * HD + d2;
    size_t base = (size_t)row * EMB;
    float x0 = x[base + c0], x1 = x[base + c0 + 32];
    float invf = exp2f(-(float)d2 * 0.4152410118609203f);
    // HW sin/cos in revolutions (v_sin_f32/v_cos_f32); err ~2.4e-4 rad << bf16 ulp
    float rev = (float)pos * invf * 0.15915494309189535f;
    rev = rev - floorf(rev);
    float sn = __builtin_amdgcn_sinf(rev);
    float cs = __builtin_amdgcn_cosf(rev);
    qr[base + c0] = (bf16)(x0 * cs - x1 * sn);
    qr[base + c0 + 32] = (bf16)(x1 * cs + x0 * sn);
    xb[base + c0] = (bf16)x0;
    xb[base + c0 + 32] = (bf16)x1;
  } else {
    int i = ((bid - 8192) * 256 + threadIdx.x) * 4;
    const float* s; bf16* d; int off;
    if (i < 3 * 1024 * 1024) { s = w0; d = o0; off = i; }
    else if (i < 4 * 1024 * 1024) { s = w1; d = o1; off = i - 3 * 1024 * 1024; }
    else { s = w2; d = o2; off = i - 4 * 1024 * 1024; }
    float4 f = *(const float4*)(s + off);
    d[off] = (bf16)f.x; d[off + 1] = (bf16)f.y;
    d[off + 2] = (bf16)f.z; d[off + 3] = (bf16)f.w;
  }
}

// ---------------- fused in-proj GEMM (v20: split-half BK=64) ---------------
// Outputs: qb[token][1024] pre-scaled by 0.125; kv images per (b,h): 32 tiles
// of 64 keys {K 4096 | V 4096} in the attention LDS layout (K scaled log2e).
__global__ __launch_bounds__(256) void gemm_in(
    const bf16* __restrict__ Aq, const bf16* __restrict__ Ax,
    const bf16* __restrict__ W, const float* __restrict__ bias,
    bf16* __restrict__ qb, bf16* __restrict__ kv) {
  __shared__ bf16 As0[128 * 32], As1[128 * 32];
  __shared__ bf16 Bs0[128 * 32], Bs1[128 * 32];
  const int tid = threadIdx.x, lane = tid & 63, wave = tid >> 6;
  const int quad = lane >> 4, l16 = lane & 15;
  const int m0 = blockIdx.y * 128, n0 = blockIdx.x * 128;
  const bf16* A = (n0 < 2048) ? Aq : Ax;
  const int K = 1024;
  const int wm = (wave >> 1) * 64, wn = (wave & 1) * 64;
  const int srow = wave * 32 + (lane >> 2);
  const int scol = (lane & 3) * 8;
  const bf16* a0 = A + (size_t)(m0 + srow) * K + scol;
  const bf16* a1 = A + (size_t)(m0 + srow + 16) * K + scol;
  const bf16* w0p = W + (size_t)(n0 + srow) * K + scol;
  const bf16* w1p = W + (size_t)(n0 + srow + 16) * K + scol;
  f32x4 acc[4][4] = {};
  for (int k0 = 0; k0 < K; k0 += 64) {
    __syncthreads();
    gll16(a0 + k0, As0 + wave * 1024);
    gll16(a1 + k0, As0 + wave * 1024 + 512);
    gll16(w0p + k0, Bs0 + wave * 1024);
    gll16(w1p + k0, Bs0 + wave * 1024 + 512);
    gll16(a0 + k0 + 32, As1 + wave * 1024);
    gll16(a1 + k0 + 32, As1 + wave * 1024 + 512);
    gll16(w0p + k0 + 32, Bs1 + wave * 1024);
    gll16(w1p + k0 + 32, Bs1 + wave * 1024 + 512);
    __syncthreads();
    {
      bf16x8 af[4], bw[4];
#pragma unroll
      for (int t = 0; t < 4; ++t) {
        af[t] = *(const bf16x8*)(As0 + (wm + t * 16 + l16) * 32 + quad * 8);
        bw[t] = *(const bf16x8*)(Bs0 + (wn + t * 16 + l16) * 32 + quad * 8);
      }
#pragma unroll
      for (int mt = 0; mt < 4; ++mt)
#pragma unroll
        for (int nt = 0; nt < 4; ++nt)
          acc[mt][nt] = mfma16(af[mt], bw[nt], acc[mt][nt]);
    }
    {
      bf16x8 af[4], bw[4];
#pragma unroll
      for (int t = 0; t < 4; ++t) {
        af[t] = *(const bf16x8*)(As1 + (wm + t * 16 + l16) * 32 + quad * 8);
        bw[t] = *(const bf16x8*)(Bs1 + (wn + t * 16 + l16) * 32 + quad * 8);
      }
#pragma unroll
      for (int mt = 0; mt < 4; ++mt)
#pragma unroll
        for (int nt = 0; nt < 4; ++nt)
          acc[mt][nt] = mfma16(af[mt], bw[nt], acc[mt][nt]);
    }
  }
  if (n0 < 1024) {
    // Q: scale 1/8 (exact in bf16)
#pragma unroll
    for (int mt = 0; mt < 4; ++mt)
      for (int nt = 0; nt < 4; ++nt) {
        const int n = n0 + wn + nt * 16 + l16;
        const float bv = bias[n];
#pragma unroll
        for (int r = 0; r < 4; ++r) {
          const int m = m0 + wm + mt * 16 + quad * 4 + r;
          qb[(size_t)m * 1024 + n] = (bf16)((acc[mt][nt][r] + bv) * 0.125f);
        }
      }
  } else if (n0 < 2048) {
    // K: scale log2(e), write into swizzled 64-key tile image
#pragma unroll
    for (int mt = 0; mt < 4; ++mt)
      for (int nt = 0; nt < 4; ++nt) {
        const int n = n0 + wn + nt * 16 + l16;
        const float bv = bias[n];
        const int kd = n - 1024, hh = kd >> 6, d = kd & 63;
        const int dc = d >> 3, dl = d & 7;
#pragma unroll
        for (int r = 0; r < 4; ++r) {
          const int m = m0 + wm + mt * 16 + quad * 4 + r;
          const int bb = m >> 11, s = m & 2047;
          const int t = s >> 6, kr = s & 63;
          const size_t base = ((size_t)((bb * 16 + hh) * 32 + t)) * 8192;
          kv[base + kr * 64 + ((dc ^ (kr & 7)) << 3) + dl] =
              (bf16)((acc[mt][nt][r] + bv) * 1.4426950408889634f);
        }
      }
  } else {
    // V: permuted+swizzled 64-key tile image, 4 tokens per bf16x4
#pragma unroll
    for (int mt = 0; mt < 4; ++mt)
      for (int nt = 0; nt < 4; ++nt) {
        const int n = n0 + wn + nt * 16 + l16;
        const float bv = bias[n];
        const int vd = n - 2048, hh = vd >> 6, d = vd & 63;
        const int m = m0 + wm + mt * 16 + quad * 4;
        const int bb = m >> 11, s = m & 2047;
        const int t = s >> 6, kt = s & 63;
        const int g = kt >> 4, w = kt & 15;
        const int c = 2 * g + ((w >> 2) & 1);
        const int slot = (w & 8) ? 4 : 0;
        const size_t base = ((size_t)((bb * 16 + hh) * 32 + t)) * 8192 + 4096;
        bf16x4 pkv;
#pragma unroll
        for (int r = 0; r < 4; ++r) pkv[r] = (bf16)(acc[mt][nt][r] + bv);
        *(bf16x4*)(kv + base + d * 64 + ((c ^ (d & 7)) << 3) + slot) = pkv;
      }
  }
}

// ---------------- GEMM 128x128 split-half BK=64: C = A @ W^T + bias -------
__global__ __launch_bounds__(256) void gemm_bt(
    const bf16* __restrict__ A, const bf16* __restrict__ W,
    const float* __restrict__ bias,
    float* __restrict__ outF, bf16* __restrict__ outB,
    int M, int N, int K) {
  __shared__ bf16 As0[128 * 32], As1[128 * 32];
  __shared__ bf16 Bs0[128 * 32], Bs1[128 * 32];
  const int tid = threadIdx.x, lane = tid & 63, wave = tid >> 6;
  const int quad = lane >> 4, l16 = lane & 15;
  const int m0 = blockIdx.y * 128, n0 = blockIdx.x * 128;
  const int wm = (wave >> 1) * 64, wn = (wave & 1) * 64;
  const int srow = wave * 32 + (lane >> 2);
  const int scol = (lane & 3) * 8;
  const bf16* a0 = A + (size_t)(m0 + srow) * K + scol;
  const bf16* a1 = A + (size_t)(m0 + srow + 16) * K + scol;
  const bf16* w0p = W + (size_t)(n0 + srow) * K + scol;
  const bf16* w1p = W + (size_t)(n0 + srow + 16) * K + scol;
  f32x4 acc[4][4] = {};
  for (int k0 = 0; k0 < K; k0 += 64) {
    __syncthreads();
    gll16(a0 + k0, As0 + wave * 1024);
    gll16(a1 + k0, As0 + wave * 1024 + 512);
    gll16(w0p + k0, Bs0 + wave * 1024);
    gll16(w1p + k0, Bs0 + wave * 1024 + 512);
    gll16(a0 + k0 + 32, As1 + wave * 1024);
    gll16(a1 + k0 + 32, As1 + wave * 1024 + 512);
    gll16(w0p + k0 + 32, Bs1 + wave * 1024);
    gll16(w1p + k0 + 32, Bs1 + wave * 1024 + 512);
    __syncthreads();
    {
      bf16x8 af[4], bw[4];
#pragma unroll
      for (int t = 0; t < 4; ++t) {
        af[t] = *(const bf16x8*)(As0 + (wm + t * 16 + l16) * 32 + quad * 8);
        bw[t] = *(const bf16x8*)(Bs0 + (wn + t * 16 + l16) * 32 + quad * 8);
      }
#pragma unroll
      for (int mt = 0; mt < 4; ++mt)
#pragma unroll
        for (int nt = 0; nt < 4; ++nt)
          acc[mt][nt] = mfma16(af[mt], bw[nt], acc[mt][nt]);
    }
    {
      bf16x8 af[4], bw[4];
#pragma unroll
      for (int t = 0; t < 4; ++t) {
        af[t] = *(const bf16x8*)(As1 + (wm + t * 16 + l16) * 32 + quad * 8);
        bw[t] = *(const bf16x8*)(Bs1 + (wn + t * 16 + l16) * 32 + quad * 8);
      }
#pragma unroll
      for (int mt = 0; mt < 4; ++mt)
#pragma unroll
        for (int nt = 0; nt < 4; ++nt)
          acc[mt][nt] = mfma16(af[mt], bw[nt], acc[mt][nt]);
    }
  }
#pragma unroll
  for (int mt = 0; mt < 4; ++mt)
    for (int nt = 0; nt < 4; ++nt) {
      const int n = n0 + wn + nt * 16 + l16;
      const float bv = bias ? bias[n] : 0.0f;
#pragma unroll
      for (int r = 0; r < 4; ++r) {
        const int m = m0 + wm + mt * 16 + quad * 4 + r;
        const float v = acc[mt][nt][r] + bv;
        if (outF) outF[(size_t)m * N + n] = v;
        if (outB) outB[(size_t)m * N + n] = (bf16)v;
      }
    }
}

// ---------------- GEMM 128x64 split-half BK=64 (out-proj) ----------------
__global__ __launch_bounds__(256) void gemm_bt64(
    const bf16* __restrict__ A, const bf16* __restrict__ W,
    const float* __restrict__ bias, float* __restrict__ outF,
    int M, int N, int K) {
  __shared__ bf16 As0[128 * 32], As1[128 * 32];
  __shared__ bf16 Bs0[64 * 32], Bs1[64 * 32];
  const int tid = threadIdx.x, lane = tid & 63, wave = tid >> 6;
  const int quad = lane >> 4, l16 = lane & 15;
  const int m0 = blockIdx.y * 128, n0 = blockIdx.x * 64;
  const int wm = (wave >> 1) * 64, wn = (wave & 1) * 32;
  const int srow = wave * 32 + (lane >> 2);
  const int srowB = wave * 16 + (lane >> 2);
  const int scol = (lane & 3) * 8;
  const bf16* a0 = A + (size_t)(m0 + srow) * K + scol;
  const bf16* a1 = A + (size_t)(m0 + srow + 16) * K + scol;
  const bf16* w0p = W + (size_t)(n0 + srowB) * K + scol;
  f32x4 acc[4][2] = {};
  for (int k0 = 0; k0 < K; k0 += 64) {
    __syncthreads();
    gll16(a0 + k0, As0 + wave * 1024);
    gll16(a1 + k0, As0 + wave * 1024 + 512);
    gll16(w0p + k0, Bs0 + wave * 512);
    gll16(a0 + k0 + 32, As1 + wave * 1024);
    gll16(a1 + k0 + 32, As1 + wave * 1024 + 512);
    gll16(w0p + k0 + 32, Bs1 + wave * 512);
    __syncthreads();
    {
      bf16x8 af[4], bw[2];
#pragma unroll
      for (int t = 0; t < 4; ++t)
        af[t] = *(const bf16x8*)(As0 + (wm + t * 16 + l16) * 32 + quad * 8);
#pragma unroll
      for (int t = 0; t < 2; ++t)
        bw[t] = *(const bf16x8*)(Bs0 + (wn + t * 16 + l16) * 32 + quad * 8);
#pragma unroll
      for (int mt = 0; mt < 4; ++mt)
#pragma unroll
        for (int nt = 0; nt < 2; ++nt)
          acc[mt][nt] = mfma16(af[mt], bw[nt], acc[mt][nt]);
    }
    {
      bf16x8 af[4], bw[2];
#pragma unroll
      for (int t = 0; t < 4; ++t)
        af[t] = *(const bf16x8*)(As1 + (wm + t * 16 + l16) * 32 + quad * 8);
#pragma unroll
      for (int t = 0; t < 2; ++t)
        bw[t] = *(const bf16x8*)(Bs1 + (wn + t * 16 + l16) * 32 + quad * 8);
#pragma unroll
      for (int mt = 0; mt < 4; ++mt)
#pragma unroll
        for (int nt = 0; nt < 2; ++nt)
          acc[mt][nt] = mfma16(af[mt], bw[nt], acc[mt][nt]);
    }
  }
#pragma unroll
  for (int mt = 0; mt < 4; ++mt)
    for (int nt = 0; nt < 2; ++nt) {
      const int n = n0 + wn + nt * 16 + l16;
      const float bv = bias[n];
#pragma unroll
      for (int r = 0; r < 4; ++r) {
        const int m = m0 + wm + mt * 16 + quad * 4 + r;
        outF[(size_t)m * N + n] = acc[mt][nt][r] + bv;
      }
    }
}

// ---------------- flash attention v14: dual-stream + counted vmcnt ---------
__global__ __launch_bounds__(256, 2) void attn14(
    const bf16* __restrict__ Q, const bf16* __restrict__ KV,
    bf16* __restrict__ ctx) {
  __shared__ __align__(16) bf16 kvb[2][16384];  // [buf][2 x (K 4096 | V 4096)]
  __shared__ float Linv[4][32];
  const int tid = threadIdx.x, lane = tid & 63, wave = tid >> 6;
  const int hi = lane >> 5, l31 = lane & 31, l7 = lane & 7;
  const int bid = blockIdx.x;
  const int hb = (bid & 7) * 4 + ((bid >> 3) & 3);
  const int qt = bid >> 5;              // 0..15
  const int h = hb & 15, b = hb >> 4;

  bf16x8 qf[4];
  {
    const int qrow = qt * 128 + wave * 32 + l31;
    const bf16* qp = Q + (size_t)(b * SEQ + qrow) * 1024 + h * HD + hi * 8;
#pragma unroll
    for (int t = 0; t < 4; ++t) qf[t] = *(const bf16x8*)(qp + t * 16);
  }
  asm volatile("s_waitcnt vmcnt(0)" ::: "memory");

  const int soff = tid * 8;
  const bf16* kvg = KV + ((size_t)(b * NH + h) * 32) * 8192 + soff;
#pragma unroll
  for (int i = 0; i < 8; ++i)
    gll16(kvg + i * 2048, kvb[0] + soff + i * 2048);
#pragma unroll
  for (int i = 0; i < 8; ++i)
    gll16(kvg + 16384 + i * 2048, kvb[1] + soff + i * 2048);

  f32x16 o0 = {}, o1 = {};
  float lpart = 0.0f;
  const f32x16 zf = {};

  for (int t = 0; t < 16; ++t) {
    if (t < 15) asm volatile("s_waitcnt vmcnt(8)" ::: "memory");
    else        asm volatile("s_waitcnt vmcnt(0)" ::: "memory");
    __builtin_amdgcn_s_barrier();
    __builtin_amdgcn_sched_barrier(0);
    const bf16* tb = kvb[t & 1];
#pragma unroll
    for (int half = 0; half < 2; ++half) {
      const bf16* ks = tb + half * 8192;
      const bf16* vs = ks + 4096;
      f32x16 s0, s1;
      __builtin_amdgcn_s_setprio(1);
      {
        const int swc = (hi ^ l7) * 8;
        bf16x8 k0 = *(const bf16x8*)(ks + l31 * 64 + swc);
        bf16x8 k1 = *(const bf16x8*)(ks + (32 + l31) * 64 + swc);
        s0 = mfma32(k0, qf[0], zf);
        s1 = mfma32(k1, qf[0], zf);
      }
#pragma unroll
      for (int tt = 1; tt < 4; ++tt) {
        const int swc = ((tt * 2 + hi) ^ l7) * 8;
        bf16x8 k0 = *(const bf16x8*)(ks + l31 * 64 + swc);
        bf16x8 k1 = *(const bf16x8*)(ks + (32 + l31) * 64 + swc);
        s0 = mfma32(k0, qf[tt], s0);
        s1 = mfma32(k1, qf[tt], s1);
      }
      __builtin_amdgcn_s_setprio(0);
      unsigned u[16];
#pragma unroll
      for (int g = 0; g < 8; ++g) {
        const int base = (g & 3) * 4;
        float e0, e1, e2, e3;
        if (g < 4) {
          e0 = __builtin_amdgcn_exp2f(s0[base]);
          e1 = __builtin_amdgcn_exp2f(s0[base + 1]);
          e2 = __builtin_amdgcn_exp2f(s0[base + 2]);
          e3 = __builtin_amdgcn_exp2f(s0[base + 3]);
        } else {
          e0 = __builtin_amdgcn_exp2f(s1[base]);
          e1 = __builtin_amdgcn_exp2f(s1[base + 1]);
          e2 = __builtin_amdgcn_exp2f(s1[base + 2]);
          e3 = __builtin_amdgcn_exp2f(s1[base + 3]);
        }
        lpart += (e0 + e1) + (e2 + e3);
        u[g * 2] = pk2(e0, e1);
        u[g * 2 + 1] = pk2(e2, e3);
      }
      __builtin_amdgcn_s_setprio(1);
#pragma unroll
      for (int kk = 0; kk < 4; ++kk) {
        union { unsigned w[4]; bf16x8 v; } fw;
        fw.w[0] = u[4 * kk]; fw.w[1] = u[4 * kk + 1];
        fw.w[2] = u[4 * kk + 2]; fw.w[3] = u[4 * kk + 3];
        const int c16 = (2 * kk + hi) ^ l7;
        bf16x8 v0 = *(const bf16x8*)(vs + l31 * 64 + c16 * 8);
        bf16x8 v1 = *(const bf16x8*)(vs + (32 + l31) * 64 + c16 * 8);
        o0 = mfma32(fw.v, v0, o0);
        o1 = mfma32(fw.v, v1, o1);
      }
      __builtin_amdgcn_s_setprio(0);
    }
    __builtin_amdgcn_sched_barrier(0);
    __builtin_amdgcn_s_barrier();
    __builtin_amdgcn_sched_barrier(0);
    if (t + 2 < 16) {
      const bf16* src = kvg + (size_t)(t + 2) * 16384;
      bf16* dst = kvb[t & 1] + soff;
#pragma unroll
      for (int i = 0; i < 8; ++i) gll16(src + i * 2048, dst + i * 2048);
    }
  }
  float ltot = lpart + __shfl_xor(lpart, 32, 64);
  if (lane < 32) Linv[wave][lane] = 1.0f / ltot;
#pragma unroll
  for (int r = 0; r < 16; ++r) {
    const int qloc = (r & 3) + 8 * (r >> 2) + 4 * hi;
    const float inv = Linv[wave][qloc];
    const int qrow = qt * 128 + wave * 32 + qloc;
    bf16* cp = ctx + (size_t)(b * SEQ + qrow) * EMB + h * HD;
    cp[l31] = (bf16)(o0[r] * inv);
    cp[32 + l31] = (bf16)(o1[r] * inv);
  }
}

// ---------------- residual + LayerNorm ----------------
__global__ __launch_bounds__(256) void ln1_k(
    const float* __restrict__ x, const float* __restrict__ ao,
    const float* __restrict__ g, const float* __restrict__ bta,
    float* __restrict__ hF, bf16* __restrict__ hB) {
  int row = blockIdx.x, tid = threadIdx.x;
  const float* xr = x + (size_t)row * EMB;
  const float* ar = ao + (size_t)row * EMB;
  float v[4], s = 0.0f, s2 = 0.0f;
#pragma unroll
  for (int i = 0; i < 4; ++i) {
    float t = xr[tid + i * 256] + ar[tid + i * 256];
    v[i] = t; s += t; s2 += t * t;
  }
#pragma unroll
  for (int off = 1; off < 64; off <<= 1) {
    s += __shfl_xor(s, off, 64);
    s2 += __shfl_xor(s2, off, 64);
  }
  __shared__ float red[8];
  int wave = tid >> 6, lane = tid & 63;
  if (lane == 0) { red[wave] = s; red[4 + wave] = s2; }
  __syncthreads();
  s = red[0] + red[1] + red[2] + red[3];
  s2 = red[4] + red[5] + red[6] + red[7];
  float mean = s * (1.0f / EMB);
  float var = s2 * (1.0f / EMB) - mean * mean;
  float inv = rsqrtf(var + 1e-5f);
#pragma unroll
  for (int i = 0; i < 4; ++i) {
    int c = tid + i * 256;
    float t = (v[i] - mean) * inv * g[c] + bta[c];
    hF[(size_t)row * EMB + c] = t;
    hB[(size_t)row * EMB + c] = (bf16)t;
  }
}

__global__ __launch_bounds__(256) void geglu_ln2(
    const float* __restrict__ h, const bf16* __restrict__ proj,
    const float* __restrict__ g, const float* __restrict__ bta,
    float* __restrict__ out) {
  int row = blockIdx.x, tid = threadIdx.x;
  const float* hr = h + (size_t)row * EMB;
  const bf16* pr = proj + (size_t)row * 2048;
  float v[4], s = 0.0f, s2 = 0.0f;
#pragma unroll
  for (int i = 0; i < 4; ++i) {
    int c = tid + i * 256;
    float val = (float)pr[c];
    float gate = (float)pr[1024 + c];
    float ge = 0.5f * gate * (1.0f + erff(gate * 0.70710678f));
    float t = hr[c] + val * ge;
    v[i] = t; s += t; s2 += t * t;
  }
#pragma unroll
  for (int off = 1; off < 64; off <<= 1) {
    s += __shfl_xor(s, off, 64);
    s2 += __shfl_xor(s2, off, 64);
  }
  __shared__ float red[8];
  int wave = tid >> 6, lane = tid & 63;
  if (lane == 0) { red[wave] = s; red[4 + wave] = s2; }
  __syncthreads();
  s = red[0] + red[1] + red[2] + red[3];
  s2 = red[4] + red[5] + red[6] + red[7];
  float mean = s * (1.0f / EMB);
  float var = s2 * (1.0f / EMB) - mean * mean;
  float inv = rsqrtf(var + 1e-5f);
#pragma unroll
  for (int i = 0; i < 4; ++i) {
    int c = tid + i * 256;
    out[(size_t)row * EMB + c] = (v[i] - mean) * inv * g[c] + bta[c];
  }
}

extern "C" void kernel_launch(void* const* d_in, const int* in_sizes, int n_in,
                              void* d_out, int out_size, void* d_ws, size_t ws_size,
                              hipStream_t stream) {
  const float* x = (const float*)d_in[0];
  const float* inW = (const float*)d_in[1];
  const float* inB = (const float*)d_in[2];
  const float* outW = (const float*)d_in[3];
  const float* opB = (const float*)d_in[4];
  const float* ggW = (const float*)d_in[5];
  const float* ggB = (const float*)d_in[6];
  const float* g1 = (const float*)d_in[7];
  const float* b1 = (const float*)d_in[8];
  const float* g2 = (const float*)d_in[9];
  const float* b2 = (const float*)d_in[10];
  float* out = (float*)d_out;
  char* ws = (char*)d_ws;
  const size_t MB = 1ull << 20;
  bf16* xb = (bf16*)(ws);              // 8 MB, dead after gemm_in
  bf16* hB = (bf16*)(ws);              // overlays xb (ln1 out)
  bf16* qr = (bf16*)(ws + 8 * MB);     // 8 MB, dead after gemm_in
  bf16* ctx = (bf16*)(ws + 8 * MB);    // overlays qr (attn output)
  bf16* wI = (bf16*)(ws + 16 * MB);    // 6 MB
  bf16* wO = (bf16*)(ws + 22 * MB);    // 2 MB
  bf16* wG = (bf16*)(ws + 24 * MB);    // 4 MB
  bf16* qb = (bf16*)(ws + 28 * MB);    // 8 MB, dead after attn
  bf16* kv = (bf16*)(ws + 36 * MB);    // 16 MB tile images, dead after attn
  bf16* projB = (bf16*)(ws + 28 * MB); // overlays qb+kv (GeGLU proj)
  float* ao = (float*)(ws + 52 * MB);  // 16 MB f32

  prep_all<<<8192 + 6144, 256, 0, stream>>>(x, xb, qr, inW, outW, ggW,
                                            wI, wO, wG);
  gemm_in<<<dim3(24, 32), 256, 0, stream>>>(qr, xb, wI, inB, qb, kv);
  attn14<<<512, 256, 0, stream>>>(qb, kv, ctx);
  gemm_bt64<<<dim3(16, 32), 256, 0, stream>>>(ctx, wO, opB, ao,
                                              NTOK, 1024, 1024);
  ln1_k<<<NTOK, 256, 0, stream>>>(x, ao, g1, b1, ao, hB);
  gemm_bt<<<dim3(16, 32), 256, 0, stream>>>(hB, wG, ggB, nullptr, projB,
                                            NTOK, 2048, 1024);
  geglu_ln2<<<NTOK, 256, 0, stream>>>(ao, projB, g2, b2, out);
}

// Round 13
// 250.166 us; speedup vs baseline: 1.0690x; 1.0294x over previous
//
#include <hip/hip_runtime.h>

// TransformerBlock on MI355X (gfx950).
// v22: glue-tensor precision diet. absmax stayed exactly 0.03125 through 12
// rounds of numeric changes -> headroom. out-proj now writes ao in bf16;
// ln1 reads bf16 ao and writes a SINGLE bf16 h (f32 hF eliminated);
// geglu_ln2's residual read uses the same bf16 h the GeGLU GEMM already
// consumes. Saves ~40MB HBM traffic (~6us). All compute kernels (gemm_in/
// gemm_bt split-half BK=64, attn14, prep_all) byte-identical to v21.

typedef __bf16 bf16;
typedef bf16 bf16x8 __attribute__((ext_vector_type(8)));
typedef bf16 bf16x4 __attribute__((ext_vector_type(4)));
typedef float f32x4 __attribute__((ext_vector_type(4)));
typedef float f32x16 __attribute__((ext_vector_type(16)));

#define EMB 1024
#define SEQ 2048
#define NTOK 4096
#define NH 16
#define HD 64

__device__ __forceinline__ f32x4 mfma16(bf16x8 a, bf16x8 b, f32x4 c) {
  return __builtin_amdgcn_mfma_f32_16x16x32_bf16(a, b, c, 0, 0, 0);
}
__device__ __forceinline__ f32x16 mfma32(bf16x8 a, bf16x8 b, f32x16 c) {
  return __builtin_amdgcn_mfma_f32_32x32x16_bf16(a, b, c, 0, 0, 0);
}

__device__ __forceinline__ void gll16(const void* g, void* l) {
  __builtin_amdgcn_global_load_lds(
      (const __attribute__((address_space(1))) void*)g,
      (__attribute__((address_space(3))) void*)l, 16, 0, 0);
}

__device__ __forceinline__ unsigned pk2(float a, float b) {
  union { bf16 h[2]; unsigned u; } t;
  t.h[0] = (bf16)a; t.h[1] = (bf16)b;
  return t.u;
}

// ---------------- fused elementwise prep (rope+cast, one launch) ----------
__global__ __launch_bounds__(256) void prep_all(
    const float* __restrict__ x, bf16* __restrict__ xb, bf16* __restrict__ qr,
    const float* __restrict__ w0, const float* __restrict__ w1,
    const float* __restrict__ w2, bf16* __restrict__ o0,
    bf16* __restrict__ o1, bf16* __restrict__ o2) {
  const int bid = blockIdx.x;
  if (bid < 8192) {
    int idx = bid * 256 + threadIdx.x;
    int row = idx >> 9;
    int i = idx & 511;
    int h = i >> 5, d2 = i & 31;
    int pos = row & (SEQ - 1);
    int c0 = h * HD + d2;
    size_t base = (size_t)row * EMB;
    float x0 = x[base + c0], x1 = x[base + c0 + 32];
    float invf = exp2f(-(float)d2 * 0.4152410118609203f);
    // HW sin/cos in revolutions; err ~2.4e-4 rad << bf16 ulp
    float rev = (float)pos * invf * 0.15915494309189535f;
    rev = rev - floorf(rev);
    float sn = __builtin_amdgcn_sinf(rev);
    float cs = __builtin_amdgcn_cosf(rev);
    qr[base + c0] = (bf16)(x0 * cs - x1 * sn);
    qr[base + c0 + 32] = (bf16)(x1 * cs + x0 * sn);
    xb[base + c0] = (bf16)x0;
    xb[base + c0 + 32] = (bf16)x1;
  } else {
    int i = ((bid - 8192) * 256 + threadIdx.x) * 4;
    const float* s; bf16* d; int off;
    if (i < 3 * 1024 * 1024) { s = w0; d = o0; off = i; }
    else if (i < 4 * 1024 * 1024) { s = w1; d = o1; off = i - 3 * 1024 * 1024; }
    else { s = w2; d = o2; off = i - 4 * 1024 * 1024; }
    float4 f = *(const float4*)(s + off);
    d[off] = (bf16)f.x; d[off + 1] = (bf16)f.y;
    d[off + 2] = (bf16)f.z; d[off + 3] = (bf16)f.w;
  }
}

// ---------------- fused in-proj GEMM (v20: split-half BK=64) ---------------
// Outputs: qb[token][1024] pre-scaled by 0.125; kv images per (b,h): 32 tiles
// of 64 keys {K 4096 | V 4096} in the attention LDS layout (K scaled log2e).
__global__ __launch_bounds__(256) void gemm_in(
    const bf16* __restrict__ Aq, const bf16* __restrict__ Ax,
    const bf16* __restrict__ W, const float* __restrict__ bias,
    bf16* __restrict__ qb, bf16* __restrict__ kv) {
  __shared__ bf16 As0[128 * 32], As1[128 * 32];
  __shared__ bf16 Bs0[128 * 32], Bs1[128 * 32];
  const int tid = threadIdx.x, lane = tid & 63, wave = tid >> 6;
  const int quad = lane >> 4, l16 = lane & 15;
  const int m0 = blockIdx.y * 128, n0 = blockIdx.x * 128;
  const bf16* A = (n0 < 2048) ? Aq : Ax;
  const int K = 1024;
  const int wm = (wave >> 1) * 64, wn = (wave & 1) * 64;
  const int srow = wave * 32 + (lane >> 2);
  const int scol = (lane & 3) * 8;
  const bf16* a0 = A + (size_t)(m0 + srow) * K + scol;
  const bf16* a1 = A + (size_t)(m0 + srow + 16) * K + scol;
  const bf16* w0p = W + (size_t)(n0 + srow) * K + scol;
  const bf16* w1p = W + (size_t)(n0 + srow + 16) * K + scol;
  f32x4 acc[4][4] = {};
  for (int k0 = 0; k0 < K; k0 += 64) {
    __syncthreads();
    gll16(a0 + k0, As0 + wave * 1024);
    gll16(a1 + k0, As0 + wave * 1024 + 512);
    gll16(w0p + k0, Bs0 + wave * 1024);
    gll16(w1p + k0, Bs0 + wave * 1024 + 512);
    gll16(a0 + k0 + 32, As1 + wave * 1024);
    gll16(a1 + k0 + 32, As1 + wave * 1024 + 512);
    gll16(w0p + k0 + 32, Bs1 + wave * 1024);
    gll16(w1p + k0 + 32, Bs1 + wave * 1024 + 512);
    __syncthreads();
    {
      bf16x8 af[4], bw[4];
#pragma unroll
      for (int t = 0; t < 4; ++t) {
        af[t] = *(const bf16x8*)(As0 + (wm + t * 16 + l16) * 32 + quad * 8);
        bw[t] = *(const bf16x8*)(Bs0 + (wn + t * 16 + l16) * 32 + quad * 8);
      }
#pragma unroll
      for (int mt = 0; mt < 4; ++mt)
#pragma unroll
        for (int nt = 0; nt < 4; ++nt)
          acc[mt][nt] = mfma16(af[mt], bw[nt], acc[mt][nt]);
    }
    {
      bf16x8 af[4], bw[4];
#pragma unroll
      for (int t = 0; t < 4; ++t) {
        af[t] = *(const bf16x8*)(As1 + (wm + t * 16 + l16) * 32 + quad * 8);
        bw[t] = *(const bf16x8*)(Bs1 + (wn + t * 16 + l16) * 32 + quad * 8);
      }
#pragma unroll
      for (int mt = 0; mt < 4; ++mt)
#pragma unroll
        for (int nt = 0; nt < 4; ++nt)
          acc[mt][nt] = mfma16(af[mt], bw[nt], acc[mt][nt]);
    }
  }
  if (n0 < 1024) {
    // Q: scale 1/8 (exact in bf16)
#pragma unroll
    for (int mt = 0; mt < 4; ++mt)
      for (int nt = 0; nt < 4; ++nt) {
        const int n = n0 + wn + nt * 16 + l16;
        const float bv = bias[n];
#pragma unroll
        for (int r = 0; r < 4; ++r) {
          const int m = m0 + wm + mt * 16 + quad * 4 + r;
          qb[(size_t)m * 1024 + n] = (bf16)((acc[mt][nt][r] + bv) * 0.125f);
        }
      }
  } else if (n0 < 2048) {
    // K: scale log2(e), write into swizzled 64-key tile image
#pragma unroll
    for (int mt = 0; mt < 4; ++mt)
      for (int nt = 0; nt < 4; ++nt) {
        const int n = n0 + wn + nt * 16 + l16;
        const float bv = bias[n];
        const int kd = n - 1024, hh = kd >> 6, d = kd & 63;
        const int dc = d >> 3, dl = d & 7;
#pragma unroll
        for (int r = 0; r < 4; ++r) {
          const int m = m0 + wm + mt * 16 + quad * 4 + r;
          const int bb = m >> 11, s = m & 2047;
          const int t = s >> 6, kr = s & 63;
          const size_t base = ((size_t)((bb * 16 + hh) * 32 + t)) * 8192;
          kv[base + kr * 64 + ((dc ^ (kr & 7)) << 3) + dl] =
              (bf16)((acc[mt][nt][r] + bv) * 1.4426950408889634f);
        }
      }
  } else {
    // V: permuted+swizzled 64-key tile image, 4 tokens per bf16x4
#pragma unroll
    for (int mt = 0; mt < 4; ++mt)
      for (int nt = 0; nt < 4; ++nt) {
        const int n = n0 + wn + nt * 16 + l16;
        const float bv = bias[n];
        const int vd = n - 2048, hh = vd >> 6, d = vd & 63;
        const int m = m0 + wm + mt * 16 + quad * 4;
        const int bb = m >> 11, s = m & 2047;
        const int t = s >> 6, kt = s & 63;
        const int g = kt >> 4, w = kt & 15;
        const int c = 2 * g + ((w >> 2) & 1);
        const int slot = (w & 8) ? 4 : 0;
        const size_t base = ((size_t)((bb * 16 + hh) * 32 + t)) * 8192 + 4096;
        bf16x4 pkv;
#pragma unroll
        for (int r = 0; r < 4; ++r) pkv[r] = (bf16)(acc[mt][nt][r] + bv);
        *(bf16x4*)(kv + base + d * 64 + ((c ^ (d & 7)) << 3) + slot) = pkv;
      }
  }
}

// ---------------- GEMM 128x128 split-half BK=64: C = A @ W^T + bias -------
__global__ __launch_bounds__(256) void gemm_bt(
    const bf16* __restrict__ A, const bf16* __restrict__ W,
    const float* __restrict__ bias,
    float* __restrict__ outF, bf16* __restrict__ outB,
    int M, int N, int K) {
  __shared__ bf16 As0[128 * 32], As1[128 * 32];
  __shared__ bf16 Bs0[128 * 32], Bs1[128 * 32];
  const int tid = threadIdx.x, lane = tid & 63, wave = tid >> 6;
  const int quad = lane >> 4, l16 = lane & 15;
  const int m0 = blockIdx.y * 128, n0 = blockIdx.x * 128;
  const int wm = (wave >> 1) * 64, wn = (wave & 1) * 64;
  const int srow = wave * 32 + (lane >> 2);
  const int scol = (lane & 3) * 8;
  const bf16* a0 = A + (size_t)(m0 + srow) * K + scol;
  const bf16* a1 = A + (size_t)(m0 + srow + 16) * K + scol;
  const bf16* w0p = W + (size_t)(n0 + srow) * K + scol;
  const bf16* w1p = W + (size_t)(n0 + srow + 16) * K + scol;
  f32x4 acc[4][4] = {};
  for (int k0 = 0; k0 < K; k0 += 64) {
    __syncthreads();
    gll16(a0 + k0, As0 + wave * 1024);
    gll16(a1 + k0, As0 + wave * 1024 + 512);
    gll16(w0p + k0, Bs0 + wave * 1024);
    gll16(w1p + k0, Bs0 + wave * 1024 + 512);
    gll16(a0 + k0 + 32, As1 + wave * 1024);
    gll16(a1 + k0 + 32, As1 + wave * 1024 + 512);
    gll16(w0p + k0 + 32, Bs1 + wave * 1024);
    gll16(w1p + k0 + 32, Bs1 + wave * 1024 + 512);
    __syncthreads();
    {
      bf16x8 af[4], bw[4];
#pragma unroll
      for (int t = 0; t < 4; ++t) {
        af[t] = *(const bf16x8*)(As0 + (wm + t * 16 + l16) * 32 + quad * 8);
        bw[t] = *(const bf16x8*)(Bs0 + (wn + t * 16 + l16) * 32 + quad * 8);
      }
#pragma unroll
      for (int mt = 0; mt < 4; ++mt)
#pragma unroll
        for (int nt = 0; nt < 4; ++nt)
          acc[mt][nt] = mfma16(af[mt], bw[nt], acc[mt][nt]);
    }
    {
      bf16x8 af[4], bw[4];
#pragma unroll
      for (int t = 0; t < 4; ++t) {
        af[t] = *(const bf16x8*)(As1 + (wm + t * 16 + l16) * 32 + quad * 8);
        bw[t] = *(const bf16x8*)(Bs1 + (wn + t * 16 + l16) * 32 + quad * 8);
      }
#pragma unroll
      for (int mt = 0; mt < 4; ++mt)
#pragma unroll
        for (int nt = 0; nt < 4; ++nt)
          acc[mt][nt] = mfma16(af[mt], bw[nt], acc[mt][nt]);
    }
  }
#pragma unroll
  for (int mt = 0; mt < 4; ++mt)
    for (int nt = 0; nt < 4; ++nt) {
      const int n = n0 + wn + nt * 16 + l16;
      const float bv = bias ? bias[n] : 0.0f;
#pragma unroll
      for (int r = 0; r < 4; ++r) {
        const int m = m0 + wm + mt * 16 + quad * 4 + r;
        const float v = acc[mt][nt][r] + bv;
        if (outF) outF[(size_t)m * N + n] = v;
        if (outB) outB[(size_t)m * N + n] = (bf16)v;
      }
    }
}

// ---------------- GEMM 128x64 split-half BK=64 (out-proj, bf16 out) -------
__global__ __launch_bounds__(256) void gemm_bt64(
    const bf16* __restrict__ A, const bf16* __restrict__ W,
    const float* __restrict__ bias, bf16* __restrict__ outB,
    int M, int N, int K) {
  __shared__ bf16 As0[128 * 32], As1[128 * 32];
  __shared__ bf16 Bs0[64 * 32], Bs1[64 * 32];
  const int tid = threadIdx.x, lane = tid & 63, wave = tid >> 6;
  const int quad = lane >> 4, l16 = lane & 15;
  const int m0 = blockIdx.y * 128, n0 = blockIdx.x * 64;
  const int wm = (wave >> 1) * 64, wn = (wave & 1) * 32;
  const int srow = wave * 32 + (lane >> 2);
  const int srowB = wave * 16 + (lane >> 2);
  const int scol = (lane & 3) * 8;
  const bf16* a0 = A + (size_t)(m0 + srow) * K + scol;
  const bf16* a1 = A + (size_t)(m0 + srow + 16) * K + scol;
  const bf16* w0p = W + (size_t)(n0 + srowB) * K + scol;
  f32x4 acc[4][2] = {};
  for (int k0 = 0; k0 < K; k0 += 64) {
    __syncthreads();
    gll16(a0 + k0, As0 + wave * 1024);
    gll16(a1 + k0, As0 + wave * 1024 + 512);
    gll16(w0p + k0, Bs0 + wave * 512);
    gll16(a0 + k0 + 32, As1 + wave * 1024);
    gll16(a1 + k0 + 32, As1 + wave * 1024 + 512);
    gll16(w0p + k0 + 32, Bs1 + wave * 512);
    __syncthreads();
    {
      bf16x8 af[4], bw[2];
#pragma unroll
      for (int t = 0; t < 4; ++t)
        af[t] = *(const bf16x8*)(As0 + (wm + t * 16 + l16) * 32 + quad * 8);
#pragma unroll
      for (int t = 0; t < 2; ++t)
        bw[t] = *(const bf16x8*)(Bs0 + (wn + t * 16 + l16) * 32 + quad * 8);
#pragma unroll
      for (int mt = 0; mt < 4; ++mt)
#pragma unroll
        for (int nt = 0; nt < 2; ++nt)
          acc[mt][nt] = mfma16(af[mt], bw[nt], acc[mt][nt]);
    }
    {
      bf16x8 af[4], bw[2];
#pragma unroll
      for (int t = 0; t < 4; ++t)
        af[t] = *(const bf16x8*)(As1 + (wm + t * 16 + l16) * 32 + quad * 8);
#pragma unroll
      for (int t = 0; t < 2; ++t)
        bw[t] = *(const bf16x8*)(Bs1 + (wn + t * 16 + l16) * 32 + quad * 8);
#pragma unroll
      for (int mt = 0; mt < 4; ++mt)
#pragma unroll
        for (int nt = 0; nt < 2; ++nt)
          acc[mt][nt] = mfma16(af[mt], bw[nt], acc[mt][nt]);
    }
  }
#pragma unroll
  for (int mt = 0; mt < 4; ++mt)
    for (int nt = 0; nt < 2; ++nt) {
      const int n = n0 + wn + nt * 16 + l16;
      const float bv = bias[n];
#pragma unroll
      for (int r = 0; r < 4; ++r) {
        const int m = m0 + wm + mt * 16 + quad * 4 + r;
        outB[(size_t)m * N + n] = (bf16)(acc[mt][nt][r] + bv);
      }
    }
}

// ---------------- flash attention v14: dual-stream + counted vmcnt ---------
__global__ __launch_bounds__(256, 2) void attn14(
    const bf16* __restrict__ Q, const bf16* __restrict__ KV,
    bf16* __restrict__ ctx) {
  __shared__ __align__(16) bf16 kvb[2][16384];  // [buf][2 x (K 4096 | V 4096)]
  __shared__ float Linv[4][32];
  const int tid = threadIdx.x, lane = tid & 63, wave = tid >> 6;
  const int hi = lane >> 5, l31 = lane & 31, l7 = lane & 7;
  const int bid = blockIdx.x;
  const int hb = (bid & 7) * 4 + ((bid >> 3) & 3);
  const int qt = bid >> 5;              // 0..15
  const int h = hb & 15, b = hb >> 4;

  bf16x8 qf[4];
  {
    const int qrow = qt * 128 + wave * 32 + l31;
    const bf16* qp = Q + (size_t)(b * SEQ + qrow) * 1024 + h * HD + hi * 8;
#pragma unroll
    for (int t = 0; t < 4; ++t) qf[t] = *(const bf16x8*)(qp + t * 16);
  }
  asm volatile("s_waitcnt vmcnt(0)" ::: "memory");

  const int soff = tid * 8;
  const bf16* kvg = KV + ((size_t)(b * NH + h) * 32) * 8192 + soff;
#pragma unroll
  for (int i = 0; i < 8; ++i)
    gll16(kvg + i * 2048, kvb[0] + soff + i * 2048);
#pragma unroll
  for (int i = 0; i < 8; ++i)
    gll16(kvg + 16384 + i * 2048, kvb[1] + soff + i * 2048);

  f32x16 o0 = {}, o1 = {};
  float lpart = 0.0f;
  const f32x16 zf = {};

  for (int t = 0; t < 16; ++t) {
    if (t < 15) asm volatile("s_waitcnt vmcnt(8)" ::: "memory");
    else        asm volatile("s_waitcnt vmcnt(0)" ::: "memory");
    __builtin_amdgcn_s_barrier();
    __builtin_amdgcn_sched_barrier(0);
    const bf16* tb = kvb[t & 1];
#pragma unroll
    for (int half = 0; half < 2; ++half) {
      const bf16* ks = tb + half * 8192;
      const bf16* vs = ks + 4096;
      f32x16 s0, s1;
      __builtin_amdgcn_s_setprio(1);
      {
        const int swc = (hi ^ l7) * 8;
        bf16x8 k0 = *(const bf16x8*)(ks + l31 * 64 + swc);
        bf16x8 k1 = *(const bf16x8*)(ks + (32 + l31) * 64 + swc);
        s0 = mfma32(k0, qf[0], zf);
        s1 = mfma32(k1, qf[0], zf);
      }
#pragma unroll
      for (int tt = 1; tt < 4; ++tt) {
        const int swc = ((tt * 2 + hi) ^ l7) * 8;
        bf16x8 k0 = *(const bf16x8*)(ks + l31 * 64 + swc);
        bf16x8 k1 = *(const bf16x8*)(ks + (32 + l31) * 64 + swc);
        s0 = mfma32(k0, qf[tt], s0);
        s1 = mfma32(k1, qf[tt], s1);
      }
      __builtin_amdgcn_s_setprio(0);
      unsigned u[16];
#pragma unroll
      for (int g = 0; g < 8; ++g) {
        const int base = (g & 3) * 4;
        float e0, e1, e2, e3;
        if (g < 4) {
          e0 = __builtin_amdgcn_exp2f(s0[base]);
          e1 = __builtin_amdgcn_exp2f(s0[base + 1]);
          e2 = __builtin_amdgcn_exp2f(s0[base + 2]);
          e3 = __builtin_amdgcn_exp2f(s0[base + 3]);
        } else {
          e0 = __builtin_amdgcn_exp2f(s1[base]);
          e1 = __builtin_amdgcn_exp2f(s1[base + 1]);
          e2 = __builtin_amdgcn_exp2f(s1[base + 2]);
          e3 = __builtin_amdgcn_exp2f(s1[base + 3]);
        }
        lpart += (e0 + e1) + (e2 + e3);
        u[g * 2] = pk2(e0, e1);
        u[g * 2 + 1] = pk2(e2, e3);
      }
      __builtin_amdgcn_s_setprio(1);
#pragma unroll
      for (int kk = 0; kk < 4; ++kk) {
        union { unsigned w[4]; bf16x8 v; } fw;
        fw.w[0] = u[4 * kk]; fw.w[1] = u[4 * kk + 1];
        fw.w[2] = u[4 * kk + 2]; fw.w[3] = u[4 * kk + 3];
        const int c16 = (2 * kk + hi) ^ l7;
        bf16x8 v0 = *(const bf16x8*)(vs + l31 * 64 + c16 * 8);
        bf16x8 v1 = *(const bf16x8*)(vs + (32 + l31) * 64 + c16 * 8);
        o0 = mfma32(fw.v, v0, o0);
        o1 = mfma32(fw.v, v1, o1);
      }
      __builtin_amdgcn_s_setprio(0);
    }
    __builtin_amdgcn_sched_barrier(0);
    __builtin_amdgcn_s_barrier();
    __builtin_amdgcn_sched_barrier(0);
    if (t + 2 < 16) {
      const bf16* src = kvg + (size_t)(t + 2) * 16384;
      bf16* dst = kvb[t & 1] + soff;
#pragma unroll
      for (int i = 0; i < 8; ++i) gll16(src + i * 2048, dst + i * 2048);
    }
  }
  float ltot = lpart + __shfl_xor(lpart, 32, 64);
  if (lane < 32) Linv[wave][lane] = 1.0f / ltot;
#pragma unroll
  for (int r = 0; r < 16; ++r) {
    const int qloc = (r & 3) + 8 * (r >> 2) + 4 * hi;
    const float inv = Linv[wave][qloc];
    const int qrow = qt * 128 + wave * 32 + qloc;
    bf16* cp = ctx + (size_t)(b * SEQ + qrow) * EMB + h * HD;
    cp[l31] = (bf16)(o0[r] * inv);
    cp[32 + l31] = (bf16)(o1[r] * inv);
  }
}

// ---------------- residual + LayerNorm (bf16 ao in, bf16 h out) ------------
__global__ __launch_bounds__(256) void ln1_k(
    const float* __restrict__ x, const bf16* __restrict__ ao,
    const float* __restrict__ g, const float* __restrict__ bta,
    bf16* __restrict__ hB) {
  int row = blockIdx.x, tid = threadIdx.x;
  const float* xr = x + (size_t)row * EMB;
  const bf16* ar = ao + (size_t)row * EMB;
  float v[4], s = 0.0f, s2 = 0.0f;
#pragma unroll
  for (int i = 0; i < 4; ++i) {
    float t = xr[tid + i * 256] + (float)ar[tid + i * 256];
    v[i] = t; s += t; s2 += t * t;
  }
#pragma unroll
  for (int off = 1; off < 64; off <<= 1) {
    s += __shfl_xor(s, off, 64);
    s2 += __shfl_xor(s2, off, 64);
  }
  __shared__ float red[8];
  int wave = tid >> 6, lane = tid & 63;
  if (lane == 0) { red[wave] = s; red[4 + wave] = s2; }
  __syncthreads();
  s = red[0] + red[1] + red[2] + red[3];
  s2 = red[4] + red[5] + red[6] + red[7];
  float mean = s * (1.0f / EMB);
  float var = s2 * (1.0f / EMB) - mean * mean;
  float inv = rsqrtf(var + 1e-5f);
#pragma unroll
  for (int i = 0; i < 4; ++i) {
    int c = tid + i * 256;
    hB[(size_t)row * EMB + c] = (bf16)((v[i] - mean) * inv * g[c] + bta[c]);
  }
}

__global__ __launch_bounds__(256) void geglu_ln2(
    const bf16* __restrict__ h, const bf16* __restrict__ proj,
    const float* __restrict__ g, const float* __restrict__ bta,
    float* __restrict__ out) {
  int row = blockIdx.x, tid = threadIdx.x;
  const bf16* hr = h + (size_t)row * EMB;
  const bf16* pr = proj + (size_t)row * 2048;
  float v[4], s = 0.0f, s2 = 0.0f;
#pragma unroll
  for (int i = 0; i < 4; ++i) {
    int c = tid + i * 256;
    float val = (float)pr[c];
    float gate = (float)pr[1024 + c];
    float ge = 0.5f * gate * (1.0f + erff(gate * 0.70710678f));
    float t = (float)hr[c] + val * ge;
    v[i] = t; s += t; s2 += t * t;
  }
#pragma unroll
  for (int off = 1; off < 64; off <<= 1) {
    s += __shfl_xor(s, off, 64);
    s2 += __shfl_xor(s2, off, 64);
  }
  __shared__ float red[8];
  int wave = tid >> 6, lane = tid & 63;
  if (lane == 0) { red[wave] = s; red[4 + wave] = s2; }
  __syncthreads();
  s = red[0] + red[1] + red[2] + red[3];
  s2 = red[4] + red[5] + red[6] + red[7];
  float mean = s * (1.0f / EMB);
  float var = s2 * (1.0f / EMB) - mean * mean;
  float inv = rsqrtf(var + 1e-5f);
#pragma unroll
  for (int i = 0; i < 4; ++i) {
    int c = tid + i * 256;
    out[(size_t)row * EMB + c] = (v[i] - mean) * inv * g[c] + bta[c];
  }
}

extern "C" void kernel_launch(void* const* d_in, const int* in_sizes, int n_in,
                              void* d_out, int out_size, void* d_ws, size_t ws_size,
                              hipStream_t stream) {
  const float* x = (const float*)d_in[0];
  const float* inW = (const float*)d_in[1];
  const float* inB = (const float*)d_in[2];
  const float* outW = (const float*)d_in[3];
  const float* opB = (const float*)d_in[4];
  const float* ggW = (const float*)d_in[5];
  const float* ggB = (const float*)d_in[6];
  const float* g1 = (const float*)d_in[7];
  const float* b1 = (const float*)d_in[8];
  const float* g2 = (const float*)d_in[9];
  const float* b2 = (const float*)d_in[10];
  float* out = (float*)d_out;
  char* ws = (char*)d_ws;
  const size_t MB = 1ull << 20;
  bf16* xb = (bf16*)(ws);              // 8 MB, dead after gemm_in
  bf16* hB = (bf16*)(ws);              // overlays xb (ln1 out; read by GeGLU
                                       // GEMM and geglu_ln2)
  bf16* qr = (bf16*)(ws + 8 * MB);     // 8 MB, dead after gemm_in
  bf16* ctx = (bf16*)(ws + 8 * MB);    // overlays qr (attn output)
  bf16* wI = (bf16*)(ws + 16 * MB);    // 6 MB
  bf16* wO = (bf16*)(ws + 22 * MB);    // 2 MB
  bf16* wG = (bf16*)(ws + 24 * MB);    // 4 MB
  bf16* qb = (bf16*)(ws + 28 * MB);    // 8 MB, dead after attn
  bf16* kv = (bf16*)(ws + 36 * MB);    // 16 MB tile images, dead after attn
  bf16* projB = (bf16*)(ws + 28 * MB); // overlays qb+kv (GeGLU proj)
  bf16* aoB = (bf16*)(ws + 52 * MB);   // 8 MB bf16 (out-proj result)

  prep_all<<<8192 + 6144, 256, 0, stream>>>(x, xb, qr, inW, outW, ggW,
                                            wI, wO, wG);
  gemm_in<<<dim3(24, 32), 256, 0, stream>>>(qr, xb, wI, inB, qb, kv);
  attn14<<<512, 256, 0, stream>>>(qb, kv, ctx);
  gemm_bt64<<<dim3(16, 32), 256, 0, stream>>>(ctx, wO, opB, aoB,
                                              NTOK, 1024, 1024);
  ln1_k<<<NTOK, 256, 0, stream>>>(x, aoB, g1, b1, hB);
  gemm_bt<<<dim3(16, 32), 256, 0, stream>>>(hB, wG, ggB, nullptr, projB,
                                            NTOK, 2048, 1024);
  geglu_ln2<<<NTOK, 256, 0, stream>>>(hB, projB, g2, b2, out);
}